// Round 1
// baseline (505.273 us; speedup 1.0000x reference)
//
#include <hip/hip_runtime.h>

// Problem constants (fixed by the reference)
#define NN 50000
#define EE 1600000
#define FIN 512
#define HH 128

#define CAP 80          // bucket capacity per dst (Poisson(32); P(deg>80) ~ 1e-11)
#define OVF_CAP 64512   // overflow list capacity (correctness net, ~never used)

// binned scatter parameters
#define GROUP 128                  // nodes per bin
#define NB ((NN + GROUP - 1) / GROUP)   // 391 bins
#define NSET 8                     // per-XCD sub-lists per bin
#define BCAP 1000                  // entries per (set,bin); mean ~511, ~22 sigma headroom + ovf net

typedef short s16x8 __attribute__((ext_vector_type(8)));
typedef float f32x4 __attribute__((ext_vector_type(4)));

static __device__ inline unsigned short f2bf(float f) {
    // fp32 -> bf16 bits, round-to-nearest-even
    unsigned u = __float_as_uint(f);
    unsigned r = (u + 0x7fffu + ((u >> 16) & 1u)) >> 16;
    return (unsigned short)r;
}

// ---------------- build kernels ----------------

// Phase 1: append edges into per-(set,bin) sub-lists. set = blockIdx&7 tracks the
// XCD round-robin so each sub-list's append frontier stays in ONE XCD's L2 ->
// full 64B-line write combining (vs 8x amplification of direct bucket scatter).
// Entry: x = src | (dstLocal<<16)  (src < 2^16, dstLocal < 128), y = w bits.
__global__ __launch_bounds__(256) void bin_scatter(const int* __restrict__ src,
                                                   const int* __restrict__ dst,
                                                   const float* __restrict__ w,
                                                   int* __restrict__ bin_cnt,
                                                   int2* __restrict__ bins,
                                                   int* __restrict__ ovf_cnt,
                                                   int4* __restrict__ ovf) {
    int e = blockIdx.x * 256 + threadIdx.x;
    if (e >= EE) return;
    int s = src[e], d = dst[e];
    float we = w[e];
    int bin = d >> 7;                 // GROUP = 128
    int set = blockIdx.x & 7;         // XCD proxy (correct for any value 0..7)
    int idx = set * NB + bin;
    int pos = atomicAdd(bin_cnt + idx, 1);
    if (pos < BCAP) {
        bins[(size_t)idx * BCAP + pos] = make_int2(s | ((d & 127) << 16), __float_as_int(we));
    } else {
        int o = atomicAdd(ovf_cnt, 1);
        if (o < OVF_CAP) ovf[o] = make_int4(s, d, __float_as_int(we), 0);
    }
}

// Phase 2: one block per bin. Scatter entries into per-node buckets (80KB window
// per bin -> stays in the local L2, full write combining). Per-node positions and
// weight sums via LDS atomics. Also writes cnt[] and deg[] (replaces deg_kernel).
__global__ __launch_bounds__(512) void bucket_build(const int* __restrict__ bin_cnt,
                                                    const int2* __restrict__ bins,
                                                    int* __restrict__ cnt,
                                                    int2* __restrict__ bucket,
                                                    float* __restrict__ deg,
                                                    int* __restrict__ ovf_cnt,
                                                    int4* __restrict__ ovf) {
    __shared__ int lcnt[GROUP];
    __shared__ float lw[GROUP];
    const int b = blockIdx.x;
    const int tid = threadIdx.x;
    if (tid < GROUP) { lcnt[tid] = 0; lw[tid] = 0.0f; }
    __syncthreads();
    const int base = b * GROUP;
    for (int s = 0; s < NSET; ++s) {
        int idx = s * NB + b;
        int n = min(bin_cnt[idx], BCAP);
        const int2* e = bins + (size_t)idx * BCAP;
        for (int i = tid; i < n; i += 512) {
            int2 en = e[i];
            int sr = en.x & 0xffff;
            int dl = (en.x >> 16) & 127;
            int pos = atomicAdd(&lcnt[dl], 1);
            if (pos < CAP) {
                bucket[(size_t)(base + dl) * CAP + pos] = make_int2(sr, en.y);
                atomicAdd(&lw[dl], __int_as_float(en.y));
            } else {
                // node exceeded CAP: divert to overflow net (deg via ovf_deg)
                int o = atomicAdd(ovf_cnt, 1);
                if (o < OVF_CAP) ovf[o] = make_int4(sr, base + dl, en.y, 0);
            }
        }
    }
    __syncthreads();
    for (int i = tid; i < GROUP; i += 512) {
        int node = base + i;
        if (node < NN) {
            cnt[node] = lcnt[i];                 // raw; consumers do min(cnt, CAP)
            deg[node] = 1.0f + lw[i];            // self-loop + bucketed weights
        }
    }
}

__global__ void ovf_deg(const int* __restrict__ ovf_cnt, const int4* __restrict__ ovf,
                        float* __restrict__ deg) {
    int n = min(*ovf_cnt, OVF_CAP);
    for (int i = blockIdx.x * blockDim.x + threadIdx.x; i < n; i += blockDim.x * gridDim.x)
        atomicAdd(deg + ovf[i].y, __int_as_float(ovf[i].z));
}

__global__ void dinv_kernel(const float* __restrict__ deg, float* __restrict__ dinv, int n) {
    int i = blockIdx.x * 256 + threadIdx.x;
    if (i < n) {
        float d = deg[i];
        dinv[i] = (d > 0.0f) ? rsqrtf(d) : 0.0f;
    }
}

// ---------------- GEMM1: h2[M,128](bf16) = dinv .* (x[M,512](f32) @ Wc[512,128](f32)) ----
// 256 threads = 4 waves in 2x2; tile 128x128; BK=32; 16x16x32 bf16 MFMA, 4x4 frags/wave.

__global__ __launch_bounds__(256) void gemm1_kernel(const float* __restrict__ A,
                                                    const float* __restrict__ B,
                                                    const float* __restrict__ dinv,
                                                    unsigned short* __restrict__ h2,
                                                    int M) {
    __shared__ short As[128][40];   // [m][k], pad to 40 (80B rows)
    __shared__ short Bs[128][40];   // [n][k]
    const int bm = blockIdx.x * 128;
    const int tid = threadIdx.x;
    const int wave = tid >> 6, lane = tid & 63;
    const int wm = wave >> 1, wn = wave & 1;
    const int mlane = lane & 15, quad = lane >> 4;

    f32x4 acc[4][4];
#pragma unroll
    for (int i = 0; i < 4; ++i)
#pragma unroll
        for (int j = 0; j < 4; ++j) acc[i][j] = (f32x4){0.f, 0.f, 0.f, 0.f};

    for (int k0 = 0; k0 < FIN; k0 += 32) {
        // A tile: 128 rows x 32 k, fp32 -> bf16. 1024 float4 tasks, 4/thread.
#pragma unroll
        for (int i = 0; i < 4; ++i) {
            int task = tid + i * 256;
            int row = task >> 3, kq = task & 7;
            int grow = bm + row;
            float4 v = make_float4(0.f, 0.f, 0.f, 0.f);
            if (grow < M) v = *(const float4*)(A + (size_t)grow * FIN + k0 + kq * 4);
            ushort4 b;
            b.x = f2bf(v.x); b.y = f2bf(v.y); b.z = f2bf(v.z); b.w = f2bf(v.w);
            *(ushort4*)&As[row][kq * 4] = b;
        }
        // B tile: 32 k x 128 n, transposed to [n][k]. 512 tasks (n, kg), 2/thread.
#pragma unroll
        for (int i = 0; i < 2; ++i) {
            int task = tid + i * 256;
            int n = task & 127, kg = task >> 7;   // kg 0..3
            unsigned short tmp[8];
#pragma unroll
            for (int j = 0; j < 8; ++j)
                tmp[j] = f2bf(B[(size_t)(k0 + kg * 8 + j) * HH + n]);
            *(s16x8*)&Bs[n][kg * 8] = *(s16x8*)tmp;
        }
        __syncthreads();

        s16x8 af[4], bfr[4];
#pragma unroll
        for (int mt = 0; mt < 4; ++mt)
            af[mt] = *(const s16x8*)&As[wm * 64 + mt * 16 + mlane][quad * 8];
#pragma unroll
        for (int nt = 0; nt < 4; ++nt)
            bfr[nt] = *(const s16x8*)&Bs[wn * 64 + nt * 16 + mlane][quad * 8];
#pragma unroll
        for (int mt = 0; mt < 4; ++mt)
#pragma unroll
            for (int nt = 0; nt < 4; ++nt)
                acc[mt][nt] = __builtin_amdgcn_mfma_f32_16x16x32_bf16(af[mt], bfr[nt], acc[mt][nt], 0, 0, 0);
        __syncthreads();
    }

    // epilogue: D[row=quad*4+r][col=lane&15] per frag; scale by dinv, store bf16
#pragma unroll
    for (int mt = 0; mt < 4; ++mt) {
#pragma unroll
        for (int r = 0; r < 4; ++r) {
            int row = bm + wm * 64 + mt * 16 + quad * 4 + r;
            if (row < M) {
                float sc = dinv[row];
#pragma unroll
                for (int nt = 0; nt < 4; ++nt) {
                    int col = wn * 64 + nt * 16 + mlane;
                    h2[(size_t)row * HH + col] = f2bf(acc[mt][nt][r] * sc);
                }
            }
        }
    }
}

// ---------------- aggregation (bf16 in / bf16 out) ----------------
// agg[d] = bf16( b_conv + dinv[d] * (h2[d] + sum_e w_e * h2[src_e]) )
// one 64-lane wave per node; each lane owns feature pair (2*lane, 2*lane+1) as packed uint.

__global__ __launch_bounds__(256) void agg_kernel(const unsigned int* __restrict__ h2u,
                                                  const int* __restrict__ cnt,
                                                  const int2* __restrict__ bucket,
                                                  const float* __restrict__ dinv,
                                                  const float* __restrict__ b_conv,
                                                  const int* __restrict__ ovf_cnt,
                                                  const int4* __restrict__ ovf,
                                                  unsigned int* __restrict__ aggu, int n) {
    int idx = blockIdx.x * 256 + threadIdx.x;
    int node = idx >> 6;
    int lane = idx & 63;
    if (node >= n) return;
    int c = min(cnt[node], CAP);
    const int2* e = bucket + node * CAP;

    unsigned self = h2u[(size_t)node * 64 + lane];
    float acc0 = __uint_as_float(self << 16);
    float acc1 = __uint_as_float(self & 0xffff0000u);

    int j = 0;
    for (; j + 1 < c; j += 2) {
        int2 e0 = e[j], e1 = e[j + 1];
        float w0 = __int_as_float(e0.y), w1 = __int_as_float(e1.y);
        unsigned u0 = h2u[(size_t)e0.x * 64 + lane];
        unsigned u1 = h2u[(size_t)e1.x * 64 + lane];
        acc0 += w0 * __uint_as_float(u0 << 16) + w1 * __uint_as_float(u1 << 16);
        acc1 += w0 * __uint_as_float(u0 & 0xffff0000u) + w1 * __uint_as_float(u1 & 0xffff0000u);
    }
    if (j < c) {
        int2 e0 = e[j];
        float w0 = __int_as_float(e0.y);
        unsigned u0 = h2u[(size_t)e0.x * 64 + lane];
        acc0 += w0 * __uint_as_float(u0 << 16);
        acc1 += w0 * __uint_as_float(u0 & 0xffff0000u);
    }

    // overflow net (ovf_n is ~always 0)
    int ovf_n = min(*ovf_cnt, OVF_CAP);
    for (int i = 0; i < ovf_n; ++i) {
        int4 v = ovf[i];
        if (v.y == node) {
            float w0 = __int_as_float(v.z);
            unsigned u0 = h2u[(size_t)v.x * 64 + lane];
            acc0 += w0 * __uint_as_float(u0 << 16);
            acc1 += w0 * __uint_as_float(u0 & 0xffff0000u);
        }
    }

    float di = dinv[node];
    float2 bc = *(const float2*)&b_conv[lane * 2];
    float v0 = bc.x + di * acc0;
    float v1 = bc.y + di * acc1;
    aggu[(size_t)node * 64 + lane] = (unsigned)f2bf(v0) | ((unsigned)f2bf(v1) << 16);
}

// ---------------- GEMM2: out[M,512](f32) = agg[M,128](bf16) @ Wl[128,512](f32) + b_lin ----

__global__ __launch_bounds__(256) void gemm2_kernel(const unsigned short* __restrict__ A,
                                                    const float* __restrict__ B,
                                                    const float* __restrict__ bias,
                                                    float* __restrict__ C,
                                                    int M) {
    __shared__ short As[128][40];
    __shared__ short Bs[128][40];
    const int bm = blockIdx.x * 128;
    const int bn = blockIdx.y * 128;
    const int tid = threadIdx.x;
    const int wave = tid >> 6, lane = tid & 63;
    const int wm = wave >> 1, wn = wave & 1;
    const int mlane = lane & 15, quad = lane >> 4;

    f32x4 acc[4][4];
#pragma unroll
    for (int i = 0; i < 4; ++i)
#pragma unroll
        for (int j = 0; j < 4; ++j) acc[i][j] = (f32x4){0.f, 0.f, 0.f, 0.f};

    for (int k0 = 0; k0 < HH; k0 += 32) {
        // A tile: 128 rows x 32 k bf16, direct copy. 512 16B tasks, 2/thread.
#pragma unroll
        for (int i = 0; i < 2; ++i) {
            int task = tid + i * 256;
            int row = task >> 2, ch = task & 3;
            int grow = bm + row;
            s16x8 v = (s16x8){0, 0, 0, 0, 0, 0, 0, 0};
            if (grow < M) v = *(const s16x8*)(A + (size_t)grow * HH + k0 + ch * 8);
            *(s16x8*)&As[row][ch * 8] = v;
        }
        // B tile: 32 k x 128 n fp32 -> bf16, transposed to [n][k].
#pragma unroll
        for (int i = 0; i < 2; ++i) {
            int task = tid + i * 256;
            int n = task & 127, kg = task >> 7;
            unsigned short tmp[8];
#pragma unroll
            for (int j = 0; j < 8; ++j)
                tmp[j] = f2bf(B[(size_t)(k0 + kg * 8 + j) * FIN + bn + n]);
            *(s16x8*)&Bs[n][kg * 8] = *(s16x8*)tmp;
        }
        __syncthreads();

        s16x8 af[4], bfr[4];
#pragma unroll
        for (int mt = 0; mt < 4; ++mt)
            af[mt] = *(const s16x8*)&As[wm * 64 + mt * 16 + mlane][quad * 8];
#pragma unroll
        for (int nt = 0; nt < 4; ++nt)
            bfr[nt] = *(const s16x8*)&Bs[wn * 64 + nt * 16 + mlane][quad * 8];
#pragma unroll
        for (int mt = 0; mt < 4; ++mt)
#pragma unroll
            for (int nt = 0; nt < 4; ++nt)
                acc[mt][nt] = __builtin_amdgcn_mfma_f32_16x16x32_bf16(af[mt], bfr[nt], acc[mt][nt], 0, 0, 0);
        __syncthreads();
    }

#pragma unroll
    for (int mt = 0; mt < 4; ++mt) {
#pragma unroll
        for (int r = 0; r < 4; ++r) {
            int row = bm + wm * 64 + mt * 16 + quad * 4 + r;
            if (row < M) {
#pragma unroll
                for (int nt = 0; nt < 4; ++nt) {
                    int col = bn + wn * 64 + nt * 16 + mlane;
                    C[(size_t)row * FIN + col] = acc[mt][nt][r] + bias[col];
                }
            }
        }
    }
}

// ---------------- launch ----------------

extern "C" void kernel_launch(void* const* d_in, const int* in_sizes, int n_in,
                              void* d_out, int out_size, void* d_ws, size_t ws_size,
                              hipStream_t stream) {
    const float* x      = (const float*)d_in[0];
    const int*   ei     = (const int*)d_in[1];
    const float* ew     = (const float*)d_in[2];
    const float* W_conv = (const float*)d_in[3];
    const float* b_conv = (const float*)d_in[4];
    const float* W_lin  = (const float*)d_in[5];
    const float* b_lin  = (const float*)d_in[6];
    float* out = (float*)d_out;

    const int* src = ei;
    const int* dst = ei + EE;

    // workspace layout (bytes, 256-aligned):
    char* ws = (char*)d_ws;
    int*            cnt     = (int*)           (ws + 0);          //   200,704
    float*          deg     = (float*)         (ws + 200704);     //   200,704
    float*          dinv    = (float*)         (ws + 401408);     //   200,704
    int*            ovf_cnt = (int*)           (ws + 602112);     //       256
    int*            bin_cnt = (int*)           (ws + 602368);     //    16,384 (8*391*4 = 12,512 used)
    int4*           ovf     = (int4*)          (ws + 618752);     // 1,032,192 (64512 entries)
    int2*           bucket  = (int2*)          (ws + 1650944);    // 32,000,000
    unsigned short* h2      = (unsigned short*)(ws + 33650944);   // 12,800,000
    unsigned short* agg     = (unsigned short*)(ws + 46450944);   // 12,800,000
    // bins ALIASES h2+agg (dead until gemm1): 8*391*1000*8 = 25,024,000 B at 33,650,944
    int2*           bins    = (int2*)          (ws + 33650944);
    // end: 59,250,944 bytes (unchanged footprint)

    hipMemsetAsync(bin_cnt, 0, NSET * NB * sizeof(int), stream);
    hipMemsetAsync(ovf_cnt, 0, sizeof(int), stream);

    const int nb_n = (NN + 255) / 256;
    const int nb_w = (NN * 64 + 255) / 256;   // one wave per node

    // build: two-phase binned scatter (write-combining friendly), fused deg
    bin_scatter<<<EE / 256, 256, 0, stream>>>(src, dst, ew, bin_cnt, bins, ovf_cnt, ovf);
    bucket_build<<<NB, 512, 0, stream>>>(bin_cnt, bins, cnt, bucket, deg, ovf_cnt, ovf);
    ovf_deg<<<4, 256, 0, stream>>>(ovf_cnt, ovf, deg);
    dinv_kernel<<<nb_n, 256, 0, stream>>>(deg, dinv, NN);

    // GEMM1: h2 = bf16(dinv .* (x @ W_conv))
    gemm1_kernel<<<dim3((NN + 127) / 128, 1), 256, 0, stream>>>(x, W_conv, dinv, h2, NN);

    // aggregation (bf16 -> bf16)
    agg_kernel<<<nb_w, 256, 0, stream>>>((const unsigned int*)h2, cnt, bucket, dinv, b_conv,
                                         ovf_cnt, ovf, (unsigned int*)agg, NN);

    // GEMM2: out = agg @ W_lin + b_lin
    gemm2_kernel<<<dim3((NN + 127) / 128, FIN / 128), 256, 0, stream>>>(agg, W_lin, b_lin, out, NN);
}

// Round 3
// 403.309 us; speedup vs baseline: 1.2528x; 1.2528x over previous
//
#include <hip/hip_runtime.h>

// Problem constants (fixed by the reference)
#define NN 50000
#define EE 1600000
#define FIN 512
#define HH 128

#define CAP 80          // bucket capacity per dst (Poisson(32); P(deg>80) ~ 1e-11)
#define OVF_CAP 64512   // overflow list capacity (per-node CAP net, ~never used)

// counting-sort parameters
#define GROUP 128                        // nodes per bin
#define NB ((NN + GROUP - 1) / GROUP)    // 391 bins
#define NBLK 256                         // edge-chunk blocks
#define EPB (EE / NBLK)                  // 6250 edges per block (exact)

typedef short s16x8 __attribute__((ext_vector_type(8)));
typedef float f32x4 __attribute__((ext_vector_type(4)));

static __device__ inline unsigned short f2bf(float f) {
    // fp32 -> bf16 bits, round-to-nearest-even
    unsigned u = __float_as_uint(f);
    unsigned r = (u + 0x7fffu + ((u >> 16) & 1u)) >> 16;
    return (unsigned short)r;
}

// ---------------- build kernels (atomic-free counting sort by bin) ----------------

// Pass 1: per-(block,bin) histogram via LDS atomics (block-local, cheap).
__global__ __launch_bounds__(256) void hist_kernel(const int* __restrict__ dst,
                                                   int* __restrict__ hist) {
    __shared__ int h[NB];
    const int tid = threadIdx.x;
    for (int i = tid; i < NB; i += 256) h[i] = 0;
    __syncthreads();
    const int base = blockIdx.x * EPB;
    for (int i = tid; i < EPB; i += 256)
        atomicAdd(&h[dst[base + i] >> 7], 1);
    __syncthreads();
    for (int i = tid; i < NB; i += 256) hist[blockIdx.x * NB + i] = h[i];
}

// Pass 2: one wave per bin — exclusive scan of hist[*][bin] over the 256 blocks.
__global__ __launch_bounds__(64) void scan_bins(const int* __restrict__ hist,
                                                int* __restrict__ off,
                                                int* __restrict__ binTotal) {
    const int bin = blockIdx.x;
    const int lane = threadIdx.x;
    int v[4];
    int s = 0;
#pragma unroll
    for (int i = 0; i < 4; ++i) { v[i] = hist[(lane * 4 + i) * NB + bin]; s += v[i]; }
    int incl = s;
#pragma unroll
    for (int d = 1; d < 64; d <<= 1) {
        int t = __shfl_up(incl, d, 64);
        if (lane >= d) incl += t;
    }
    int run = incl - s;   // exclusive prefix of this lane's 4 blocks
#pragma unroll
    for (int i = 0; i < 4; ++i) { off[(lane * 4 + i) * NB + bin] = run; run += v[i]; }
    if (lane == 63) binTotal[bin] = incl;
}

// Pass 3: exclusive scan over the 391 bin totals (single block).
__global__ __launch_bounds__(512) void bin_base(const int* __restrict__ binTotal,
                                                int* __restrict__ binBase) {
    __shared__ int s[512];
    const int t = threadIdx.x;
    int mine = (t < NB) ? binTotal[t] : 0;
    s[t] = mine;
    __syncthreads();
    for (int d = 1; d < 512; d <<= 1) {
        int v = (t >= d) ? s[t - d] : 0;
        __syncthreads();
        s[t] += v;
        __syncthreads();
    }
    if (t < NB) binBase[t] = s[t] - mine;   // exclusive
}

// Pass 4: deterministic placement. LDS cursors seeded from scanned offsets —
// zero global atomics; every bins[] slot written exactly once.
// Entry: x = src | (dstLocal<<16)  (src < 2^16, dstLocal < 128), y = w bits.
__global__ __launch_bounds__(256) void place_kernel(const int* __restrict__ src,
                                                    const int* __restrict__ dst,
                                                    const float* __restrict__ w,
                                                    const int* __restrict__ off,
                                                    const int* __restrict__ binBase,
                                                    int2* __restrict__ bins) {
    __shared__ int cur[NB];
    const int tid = threadIdx.x;
    for (int i = tid; i < NB; i += 256)
        cur[i] = binBase[i] + off[blockIdx.x * NB + i];
    __syncthreads();
    const int base = blockIdx.x * EPB;
    for (int i = tid; i < EPB; i += 256) {
        int e = base + i;
        int s = src[e], d = dst[e];
        float we = w[e];
        int pos = atomicAdd(&cur[d >> 7], 1);
        bins[pos] = make_int2(s | ((d & 127) << 16), __float_as_int(we));
    }
}

// Pass 5: one block per bin. Scatter entries into per-node buckets (80KB window
// per bin, L2-resident). Per-node positions and weight sums via LDS atomics.
// Also writes cnt[] and deg[].
__global__ __launch_bounds__(512) void bucket_build(const int* __restrict__ binBase,
                                                    const int* __restrict__ binTotal,
                                                    const int2* __restrict__ bins,
                                                    int* __restrict__ cnt,
                                                    int2* __restrict__ bucket,
                                                    float* __restrict__ deg,
                                                    int* __restrict__ ovf_cnt,
                                                    int4* __restrict__ ovf) {
    __shared__ int lcnt[GROUP];
    __shared__ float lw[GROUP];
    const int b = blockIdx.x;
    const int tid = threadIdx.x;
    if (tid < GROUP) { lcnt[tid] = 0; lw[tid] = 0.0f; }
    __syncthreads();
    const int base = b * GROUP;
    const int start = binBase[b];
    const int n = binTotal[b];
    for (int i = tid; i < n; i += 512) {
        int2 en = bins[start + i];
        int sr = en.x & 0xffff;
        int dl = (en.x >> 16) & 127;
        int pos = atomicAdd(&lcnt[dl], 1);
        if (pos < CAP) {
            bucket[(size_t)(base + dl) * CAP + pos] = make_int2(sr, en.y);
            atomicAdd(&lw[dl], __int_as_float(en.y));
        } else {
            // node exceeded CAP: divert to overflow net (deg via ovf_deg)
            int o = atomicAdd(ovf_cnt, 1);
            if (o < OVF_CAP) ovf[o] = make_int4(sr, base + dl, en.y, 0);
        }
    }
    __syncthreads();
    for (int i = tid; i < GROUP; i += 512) {
        int node = base + i;
        if (node < NN) {
            cnt[node] = lcnt[i];                 // raw; consumers do min(cnt, CAP)
            deg[node] = 1.0f + lw[i];            // self-loop + bucketed weights
        }
    }
}

__global__ void ovf_deg(const int* __restrict__ ovf_cnt, const int4* __restrict__ ovf,
                        float* __restrict__ deg) {
    int n = min(*ovf_cnt, OVF_CAP);
    for (int i = blockIdx.x * blockDim.x + threadIdx.x; i < n; i += blockDim.x * gridDim.x)
        atomicAdd(deg + ovf[i].y, __int_as_float(ovf[i].z));
}

__global__ void dinv_kernel(const float* __restrict__ deg, float* __restrict__ dinv, int n) {
    int i = blockIdx.x * 256 + threadIdx.x;
    if (i < n) {
        float d = deg[i];
        dinv[i] = (d > 0.0f) ? rsqrtf(d) : 0.0f;
    }
}

// ---------------- GEMM1: h2[M,128](bf16) = dinv .* (x[M,512](f32) @ Wc[512,128](f32)) ----
// 256 threads = 4 waves in 2x2; tile 128x128; BK=32; 16x16x32 bf16 MFMA, 4x4 frags/wave.

__global__ __launch_bounds__(256) void gemm1_kernel(const float* __restrict__ A,
                                                    const float* __restrict__ B,
                                                    const float* __restrict__ dinv,
                                                    unsigned short* __restrict__ h2,
                                                    int M) {
    __shared__ short As[128][40];   // [m][k], pad to 40 (80B rows)
    __shared__ short Bs[128][40];   // [n][k]
    const int bm = blockIdx.x * 128;
    const int tid = threadIdx.x;
    const int wave = tid >> 6, lane = tid & 63;
    const int wm = wave >> 1, wn = wave & 1;
    const int mlane = lane & 15, quad = lane >> 4;

    f32x4 acc[4][4];
#pragma unroll
    for (int i = 0; i < 4; ++i)
#pragma unroll
        for (int j = 0; j < 4; ++j) acc[i][j] = (f32x4){0.f, 0.f, 0.f, 0.f};

    for (int k0 = 0; k0 < FIN; k0 += 32) {
        // A tile: 128 rows x 32 k, fp32 -> bf16. 1024 float4 tasks, 4/thread.
#pragma unroll
        for (int i = 0; i < 4; ++i) {
            int task = tid + i * 256;
            int row = task >> 3, kq = task & 7;
            int grow = bm + row;
            float4 v = make_float4(0.f, 0.f, 0.f, 0.f);
            if (grow < M) v = *(const float4*)(A + (size_t)grow * FIN + k0 + kq * 4);
            ushort4 b;
            b.x = f2bf(v.x); b.y = f2bf(v.y); b.z = f2bf(v.z); b.w = f2bf(v.w);
            *(ushort4*)&As[row][kq * 4] = b;
        }
        // B tile: 32 k x 128 n, transposed to [n][k]. 512 tasks (n, kg), 2/thread.
#pragma unroll
        for (int i = 0; i < 2; ++i) {
            int task = tid + i * 256;
            int n = task & 127, kg = task >> 7;   // kg 0..3
            unsigned short tmp[8];
#pragma unroll
            for (int j = 0; j < 8; ++j)
                tmp[j] = f2bf(B[(size_t)(k0 + kg * 8 + j) * HH + n]);
            *(s16x8*)&Bs[n][kg * 8] = *(s16x8*)tmp;
        }
        __syncthreads();

        s16x8 af[4], bfr[4];
#pragma unroll
        for (int mt = 0; mt < 4; ++mt)
            af[mt] = *(const s16x8*)&As[wm * 64 + mt * 16 + mlane][quad * 8];
#pragma unroll
        for (int nt = 0; nt < 4; ++nt)
            bfr[nt] = *(const s16x8*)&Bs[wn * 64 + nt * 16 + mlane][quad * 8];
#pragma unroll
        for (int mt = 0; mt < 4; ++mt)
#pragma unroll
            for (int nt = 0; nt < 4; ++nt)
                acc[mt][nt] = __builtin_amdgcn_mfma_f32_16x16x32_bf16(af[mt], bfr[nt], acc[mt][nt], 0, 0, 0);
        __syncthreads();
    }

    // epilogue: D[row=quad*4+r][col=lane&15] per frag; scale by dinv, store bf16
#pragma unroll
    for (int mt = 0; mt < 4; ++mt) {
#pragma unroll
        for (int r = 0; r < 4; ++r) {
            int row = bm + wm * 64 + mt * 16 + quad * 4 + r;
            if (row < M) {
                float sc = dinv[row];
#pragma unroll
                for (int nt = 0; nt < 4; ++nt) {
                    int col = wn * 64 + nt * 16 + mlane;
                    h2[(size_t)row * HH + col] = f2bf(acc[mt][nt][r] * sc);
                }
            }
        }
    }
}

// ---------------- aggregation (bf16 in / bf16 out) ----------------
// agg[d] = bf16( b_conv + dinv[d] * (h2[d] + sum_e w_e * h2[src_e]) )
// one 64-lane wave per node; each lane owns feature pair (2*lane, 2*lane+1) as packed uint.

__global__ __launch_bounds__(256) void agg_kernel(const unsigned int* __restrict__ h2u,
                                                  const int* __restrict__ cnt,
                                                  const int2* __restrict__ bucket,
                                                  const float* __restrict__ dinv,
                                                  const float* __restrict__ b_conv,
                                                  const int* __restrict__ ovf_cnt,
                                                  const int4* __restrict__ ovf,
                                                  unsigned int* __restrict__ aggu, int n) {
    int idx = blockIdx.x * 256 + threadIdx.x;
    int node = idx >> 6;
    int lane = idx & 63;
    if (node >= n) return;
    int c = min(cnt[node], CAP);
    const int2* e = bucket + node * CAP;

    unsigned self = h2u[(size_t)node * 64 + lane];
    float acc0 = __uint_as_float(self << 16);
    float acc1 = __uint_as_float(self & 0xffff0000u);

    int j = 0;
    for (; j + 1 < c; j += 2) {
        int2 e0 = e[j], e1 = e[j + 1];
        float w0 = __int_as_float(e0.y), w1 = __int_as_float(e1.y);
        unsigned u0 = h2u[(size_t)e0.x * 64 + lane];
        unsigned u1 = h2u[(size_t)e1.x * 64 + lane];
        acc0 += w0 * __uint_as_float(u0 << 16) + w1 * __uint_as_float(u1 << 16);
        acc1 += w0 * __uint_as_float(u0 & 0xffff0000u) + w1 * __uint_as_float(u1 & 0xffff0000u);
    }
    if (j < c) {
        int2 e0 = e[j];
        float w0 = __int_as_float(e0.y);
        unsigned u0 = h2u[(size_t)e0.x * 64 + lane];
        acc0 += w0 * __uint_as_float(u0 << 16);
        acc1 += w0 * __uint_as_float(u0 & 0xffff0000u);
    }

    // overflow net (ovf_n is ~always 0)
    int ovf_n = min(*ovf_cnt, OVF_CAP);
    for (int i = 0; i < ovf_n; ++i) {
        int4 v = ovf[i];
        if (v.y == node) {
            float w0 = __int_as_float(v.z);
            unsigned u0 = h2u[(size_t)v.x * 64 + lane];
            acc0 += w0 * __uint_as_float(u0 << 16);
            acc1 += w0 * __uint_as_float(u0 & 0xffff0000u);
        }
    }

    float di = dinv[node];
    float2 bc = *(const float2*)&b_conv[lane * 2];
    float v0 = bc.x + di * acc0;
    float v1 = bc.y + di * acc1;
    aggu[(size_t)node * 64 + lane] = (unsigned)f2bf(v0) | ((unsigned)f2bf(v1) << 16);
}

// ---------------- GEMM2: out[M,512](f32) = agg[M,128](bf16) @ Wl[128,512](f32) + b_lin ----

__global__ __launch_bounds__(256) void gemm2_kernel(const unsigned short* __restrict__ A,
                                                    const float* __restrict__ B,
                                                    const float* __restrict__ bias,
                                                    float* __restrict__ C,
                                                    int M) {
    __shared__ short As[128][40];
    __shared__ short Bs[128][40];
    const int bm = blockIdx.x * 128;
    const int bn = blockIdx.y * 128;
    const int tid = threadIdx.x;
    const int wave = tid >> 6, lane = tid & 63;
    const int wm = wave >> 1, wn = wave & 1;
    const int mlane = lane & 15, quad = lane >> 4;

    f32x4 acc[4][4];
#pragma unroll
    for (int i = 0; i < 4; ++i)
#pragma unroll
        for (int j = 0; j < 4; ++j) acc[i][j] = (f32x4){0.f, 0.f, 0.f, 0.f};

    for (int k0 = 0; k0 < HH; k0 += 32) {
        // A tile: 128 rows x 32 k bf16, direct copy. 512 16B tasks, 2/thread.
#pragma unroll
        for (int i = 0; i < 2; ++i) {
            int task = tid + i * 256;
            int row = task >> 2, ch = task & 3;
            int grow = bm + row;
            s16x8 v = (s16x8){0, 0, 0, 0, 0, 0, 0, 0};
            if (grow < M) v = *(const s16x8*)(A + (size_t)grow * HH + k0 + ch * 8);
            *(s16x8*)&As[row][ch * 8] = v;
        }
        // B tile: 32 k x 128 n fp32 -> bf16, transposed to [n][k].
#pragma unroll
        for (int i = 0; i < 2; ++i) {
            int task = tid + i * 256;
            int n = task & 127, kg = task >> 7;
            unsigned short tmp[8];
#pragma unroll
            for (int j = 0; j < 8; ++j)
                tmp[j] = f2bf(B[(size_t)(k0 + kg * 8 + j) * FIN + bn + n]);
            *(s16x8*)&Bs[n][kg * 8] = *(s16x8*)tmp;
        }
        __syncthreads();

        s16x8 af[4], bfr[4];
#pragma unroll
        for (int mt = 0; mt < 4; ++mt)
            af[mt] = *(const s16x8*)&As[wm * 64 + mt * 16 + mlane][quad * 8];
#pragma unroll
        for (int nt = 0; nt < 4; ++nt)
            bfr[nt] = *(const s16x8*)&Bs[wn * 64 + nt * 16 + mlane][quad * 8];
#pragma unroll
        for (int mt = 0; mt < 4; ++mt)
#pragma unroll
            for (int nt = 0; nt < 4; ++nt)
                acc[mt][nt] = __builtin_amdgcn_mfma_f32_16x16x32_bf16(af[mt], bfr[nt], acc[mt][nt], 0, 0, 0);
        __syncthreads();
    }

#pragma unroll
    for (int mt = 0; mt < 4; ++mt) {
#pragma unroll
        for (int r = 0; r < 4; ++r) {
            int row = bm + wm * 64 + mt * 16 + quad * 4 + r;
            if (row < M) {
#pragma unroll
                for (int nt = 0; nt < 4; ++nt) {
                    int col = bn + wn * 64 + nt * 16 + mlane;
                    C[(size_t)row * FIN + col] = acc[mt][nt][r] + bias[col];
                }
            }
        }
    }
}

// ---------------- launch ----------------

extern "C" void kernel_launch(void* const* d_in, const int* in_sizes, int n_in,
                              void* d_out, int out_size, void* d_ws, size_t ws_size,
                              hipStream_t stream) {
    const float* x      = (const float*)d_in[0];
    const int*   ei     = (const int*)d_in[1];
    const float* ew     = (const float*)d_in[2];
    const float* W_conv = (const float*)d_in[3];
    const float* b_conv = (const float*)d_in[4];
    const float* W_lin  = (const float*)d_in[5];
    const float* b_lin  = (const float*)d_in[6];
    float* out = (float*)d_out;

    const int* src = ei;
    const int* dst = ei + EE;

    // workspace layout (bytes, 256-aligned):
    char* ws = (char*)d_ws;
    int*            cnt      = (int*)           (ws + 0);          //   200,704
    float*          deg      = (float*)         (ws + 200704);     //   200,704
    float*          dinv     = (float*)         (ws + 401408);     //   200,704
    int*            ovf_cnt  = (int*)           (ws + 602112);     //       256
    int*            binTotal = (int*)           (ws + 602368);     //     1,792
    int*            binBase  = (int*)           (ws + 604160);     //     1,792
    int4*           ovf      = (int4*)          (ws + 605952);     // 1,032,192 (64512 entries) -> 1,638,144
    int2*           bucket   = (int2*)          (ws + 1650944);    // 32,000,000 -> 33,650,944
    unsigned short* h2       = (unsigned short*)(ws + 33650944);   // 12,800,000
    unsigned short* agg      = (unsigned short*)(ws + 46450944);   // 12,800,000
    // end: 59,250,944 bytes (unchanged footprint)

    // hist/off ALIAS the bucket region (dead until bucket_build writes bucket):
    int*            hist     = (int*)           (ws + 1650944);    //   400,640 (256*391*4)
    int*            off      = (int*)           (ws + 2051584);    //   400,640
    // bins ALIASES h2 (dead until gemm1): 1.6M * 8B = 12,800,000 exactly
    int2*           bins     = (int2*)          (ws + 33650944);

    hipMemsetAsync(ovf_cnt, 0, sizeof(int), stream);

    const int nb_n = (NN + 255) / 256;
    const int nb_w = (NN * 64 + 255) / 256;   // one wave per node

    // build: atomic-free counting sort by bin, then per-bin bucket build (LDS atomics)
    hist_kernel<<<NBLK, 256, 0, stream>>>(dst, hist);
    scan_bins<<<NB, 64, 0, stream>>>(hist, off, binTotal);
    bin_base<<<1, 512, 0, stream>>>(binTotal, binBase);
    place_kernel<<<NBLK, 256, 0, stream>>>(src, dst, ew, off, binBase, bins);
    bucket_build<<<NB, 512, 0, stream>>>(binBase, binTotal, bins, cnt, bucket, deg, ovf_cnt, ovf);
    ovf_deg<<<4, 256, 0, stream>>>(ovf_cnt, ovf, deg);
    dinv_kernel<<<nb_n, 256, 0, stream>>>(deg, dinv, NN);

    // GEMM1: h2 = bf16(dinv .* (x @ W_conv))
    gemm1_kernel<<<dim3((NN + 127) / 128, 1), 256, 0, stream>>>(x, W_conv, dinv, h2, NN);

    // aggregation (bf16 -> bf16)
    agg_kernel<<<nb_w, 256, 0, stream>>>((const unsigned int*)h2, cnt, bucket, dinv, b_conv,
                                         ovf_cnt, ovf, (unsigned int*)agg, NN);

    // GEMM2: out = agg @ W_lin + b_lin
    gemm2_kernel<<<dim3((NN + 127) / 128, FIN / 128), 256, 0, stream>>>(agg, W_lin, b_lin, out, NN);
}

// Round 4
// 373.994 us; speedup vs baseline: 1.3510x; 1.0784x over previous
//
#include <hip/hip_runtime.h>

// Problem constants (fixed by the reference)
#define NN 50000
#define EE 1600000
#define FIN 512
#define HH 128

#define CAP 80          // bucket capacity per dst (Poisson(32); P(deg>80) ~ 1e-11)
#define OVF_CAP 64512   // overflow list capacity (per-node CAP net, ~never used)

// counting-sort parameters
#define GROUP 128                        // nodes per bin
#define NB ((NN + GROUP - 1) / GROUP)    // 391 bins
#define NBLK 256                         // edge-chunk blocks
#define EPB (EE / NBLK)                  // 6250 edges per block (exact)

typedef short s16x8 __attribute__((ext_vector_type(8)));
typedef float f32x4 __attribute__((ext_vector_type(4)));

static __device__ inline unsigned short f2bf(float f) {
    // fp32 -> bf16 bits, round-to-nearest-even
    unsigned u = __float_as_uint(f);
    unsigned r = (u + 0x7fffu + ((u >> 16) & 1u)) >> 16;
    return (unsigned short)r;
}

static __device__ inline float blo(unsigned u) { return __uint_as_float(u << 16); }
static __device__ inline float bhi(unsigned u) { return __uint_as_float(u & 0xffff0000u); }

// ---------------- build kernels (atomic-free counting sort by bin) ----------------

// Pass 1: per-(block,bin) histogram via LDS atomics (block-local, cheap).
__global__ __launch_bounds__(256) void hist_kernel(const int* __restrict__ dst,
                                                   int* __restrict__ hist) {
    __shared__ int h[NB];
    const int tid = threadIdx.x;
    for (int i = tid; i < NB; i += 256) h[i] = 0;
    __syncthreads();
    const int base = blockIdx.x * EPB;
    for (int i = tid; i < EPB; i += 256)
        atomicAdd(&h[dst[base + i] >> 7], 1);
    __syncthreads();
    for (int i = tid; i < NB; i += 256) hist[blockIdx.x * NB + i] = h[i];
}

// Pass 2: one wave per bin — exclusive scan of hist[*][bin] over the 256 blocks.
__global__ __launch_bounds__(64) void scan_bins(const int* __restrict__ hist,
                                                int* __restrict__ off,
                                                int* __restrict__ binTotal) {
    const int bin = blockIdx.x;
    const int lane = threadIdx.x;
    int v[4];
    int s = 0;
#pragma unroll
    for (int i = 0; i < 4; ++i) { v[i] = hist[(lane * 4 + i) * NB + bin]; s += v[i]; }
    int incl = s;
#pragma unroll
    for (int d = 1; d < 64; d <<= 1) {
        int t = __shfl_up(incl, d, 64);
        if (lane >= d) incl += t;
    }
    int run = incl - s;   // exclusive prefix of this lane's 4 blocks
#pragma unroll
    for (int i = 0; i < 4; ++i) { off[(lane * 4 + i) * NB + bin] = run; run += v[i]; }
    if (lane == 63) binTotal[bin] = incl;
}

// Pass 3: exclusive scan over the 391 bin totals (single block).
__global__ __launch_bounds__(512) void bin_base(const int* __restrict__ binTotal,
                                                int* __restrict__ binBase) {
    __shared__ int s[512];
    const int t = threadIdx.x;
    int mine = (t < NB) ? binTotal[t] : 0;
    s[t] = mine;
    __syncthreads();
    for (int d = 1; d < 512; d <<= 1) {
        int v = (t >= d) ? s[t - d] : 0;
        __syncthreads();
        s[t] += v;
        __syncthreads();
    }
    if (t < NB) binBase[t] = s[t] - mine;   // exclusive
}

// Pass 4: deterministic placement. LDS cursors seeded from scanned offsets —
// zero global atomics; every bins[] slot written exactly once.
// Entry: x = src | (dstLocal<<16)  (src < 2^16, dstLocal < 128), y = w bits.
__global__ __launch_bounds__(256) void place_kernel(const int* __restrict__ src,
                                                    const int* __restrict__ dst,
                                                    const float* __restrict__ w,
                                                    const int* __restrict__ off,
                                                    const int* __restrict__ binBase,
                                                    int2* __restrict__ bins) {
    __shared__ int cur[NB];
    const int tid = threadIdx.x;
    for (int i = tid; i < NB; i += 256)
        cur[i] = binBase[i] + off[blockIdx.x * NB + i];
    __syncthreads();
    const int base = blockIdx.x * EPB;
    for (int i = tid; i < EPB; i += 256) {
        int e = base + i;
        int s = src[e], d = dst[e];
        float we = w[e];
        int pos = atomicAdd(&cur[d >> 7], 1);
        bins[pos] = make_int2(s | ((d & 127) << 16), __float_as_int(we));
    }
}

// Pass 5: one block per bin. Scatter entries into per-node buckets (80KB window
// per bin, L2-resident). Per-node positions and weight sums via LDS atomics.
// Also writes cnt[] and deg[].
__global__ __launch_bounds__(512) void bucket_build(const int* __restrict__ binBase,
                                                    const int* __restrict__ binTotal,
                                                    const int2* __restrict__ bins,
                                                    int* __restrict__ cnt,
                                                    int2* __restrict__ bucket,
                                                    float* __restrict__ deg,
                                                    int* __restrict__ ovf_cnt,
                                                    int4* __restrict__ ovf) {
    __shared__ int lcnt[GROUP];
    __shared__ float lw[GROUP];
    const int b = blockIdx.x;
    const int tid = threadIdx.x;
    if (tid < GROUP) { lcnt[tid] = 0; lw[tid] = 0.0f; }
    __syncthreads();
    const int base = b * GROUP;
    const int start = binBase[b];
    const int n = binTotal[b];
    for (int i = tid; i < n; i += 512) {
        int2 en = bins[start + i];
        int sr = en.x & 0xffff;
        int dl = (en.x >> 16) & 127;
        int pos = atomicAdd(&lcnt[dl], 1);
        if (pos < CAP) {
            bucket[(size_t)(base + dl) * CAP + pos] = make_int2(sr, en.y);
            atomicAdd(&lw[dl], __int_as_float(en.y));
        } else {
            // node exceeded CAP: divert to overflow net (deg via ovf_deg)
            int o = atomicAdd(ovf_cnt, 1);
            if (o < OVF_CAP) ovf[o] = make_int4(sr, base + dl, en.y, 0);
        }
    }
    __syncthreads();
    for (int i = tid; i < GROUP; i += 512) {
        int node = base + i;
        if (node < NN) {
            cnt[node] = lcnt[i];                 // raw; consumers do min(cnt, CAP)
            deg[node] = 1.0f + lw[i];            // self-loop + bucketed weights
        }
    }
}

__global__ void ovf_deg(const int* __restrict__ ovf_cnt, const int4* __restrict__ ovf,
                        float* __restrict__ deg) {
    int n = min(*ovf_cnt, OVF_CAP);
    for (int i = blockIdx.x * blockDim.x + threadIdx.x; i < n; i += blockDim.x * gridDim.x)
        atomicAdd(deg + ovf[i].y, __int_as_float(ovf[i].z));
}

__global__ void dinv_kernel(const float* __restrict__ deg, float* __restrict__ dinv, int n) {
    int i = blockIdx.x * 256 + threadIdx.x;
    if (i < n) {
        float d = deg[i];
        dinv[i] = (d > 0.0f) ? rsqrtf(d) : 0.0f;
    }
}

// ---------------- GEMM1: h2[M,128](bf16) = dinv .* (x[M,512](f32) @ Wc[512,128](f32)) ----
// 256 threads = 4 waves in 2x2; tile 128x128; BK=32; 16x16x32 bf16 MFMA, 4x4 frags/wave.

__global__ __launch_bounds__(256) void gemm1_kernel(const float* __restrict__ A,
                                                    const float* __restrict__ B,
                                                    const float* __restrict__ dinv,
                                                    unsigned short* __restrict__ h2,
                                                    int M) {
    __shared__ short As[128][40];   // [m][k], pad to 40 (80B rows)
    __shared__ short Bs[128][40];   // [n][k]
    const int bm = blockIdx.x * 128;
    const int tid = threadIdx.x;
    const int wave = tid >> 6, lane = tid & 63;
    const int wm = wave >> 1, wn = wave & 1;
    const int mlane = lane & 15, quad = lane >> 4;

    f32x4 acc[4][4];
#pragma unroll
    for (int i = 0; i < 4; ++i)
#pragma unroll
        for (int j = 0; j < 4; ++j) acc[i][j] = (f32x4){0.f, 0.f, 0.f, 0.f};

    for (int k0 = 0; k0 < FIN; k0 += 32) {
        // A tile: 128 rows x 32 k, fp32 -> bf16. 1024 float4 tasks, 4/thread.
#pragma unroll
        for (int i = 0; i < 4; ++i) {
            int task = tid + i * 256;
            int row = task >> 3, kq = task & 7;
            int grow = bm + row;
            float4 v = make_float4(0.f, 0.f, 0.f, 0.f);
            if (grow < M) v = *(const float4*)(A + (size_t)grow * FIN + k0 + kq * 4);
            ushort4 b;
            b.x = f2bf(v.x); b.y = f2bf(v.y); b.z = f2bf(v.z); b.w = f2bf(v.w);
            *(ushort4*)&As[row][kq * 4] = b;
        }
        // B tile: 32 k x 128 n, transposed to [n][k]. 512 tasks (n, kg), 2/thread.
#pragma unroll
        for (int i = 0; i < 2; ++i) {
            int task = tid + i * 256;
            int n = task & 127, kg = task >> 7;   // kg 0..3
            unsigned short tmp[8];
#pragma unroll
            for (int j = 0; j < 8; ++j)
                tmp[j] = f2bf(B[(size_t)(k0 + kg * 8 + j) * HH + n]);
            *(s16x8*)&Bs[n][kg * 8] = *(s16x8*)tmp;
        }
        __syncthreads();

        s16x8 af[4], bfr[4];
#pragma unroll
        for (int mt = 0; mt < 4; ++mt)
            af[mt] = *(const s16x8*)&As[wm * 64 + mt * 16 + mlane][quad * 8];
#pragma unroll
        for (int nt = 0; nt < 4; ++nt)
            bfr[nt] = *(const s16x8*)&Bs[wn * 64 + nt * 16 + mlane][quad * 8];
#pragma unroll
        for (int mt = 0; mt < 4; ++mt)
#pragma unroll
            for (int nt = 0; nt < 4; ++nt)
                acc[mt][nt] = __builtin_amdgcn_mfma_f32_16x16x32_bf16(af[mt], bfr[nt], acc[mt][nt], 0, 0, 0);
        __syncthreads();
    }

    // epilogue: D[row=quad*4+r][col=lane&15] per frag; scale by dinv, store bf16
#pragma unroll
    for (int mt = 0; mt < 4; ++mt) {
#pragma unroll
        for (int r = 0; r < 4; ++r) {
            int row = bm + wm * 64 + mt * 16 + quad * 4 + r;
            if (row < M) {
                float sc = dinv[row];
#pragma unroll
                for (int nt = 0; nt < 4; ++nt) {
                    int col = wn * 64 + nt * 16 + mlane;
                    h2[(size_t)row * HH + col] = f2bf(acc[mt][nt][r] * sc);
                }
            }
        }
    }
}

// ---------------- aggregation (bf16 in / bf16 out) ----------------
// agg[d] = bf16( b_conv + dinv[d] * (h2[d] + sum_e w_e * h2[src_e]) )
// one 64-lane wave per node; each lane owns feature pair (2*lane, 2*lane+1) as packed uint.
// Unroll-8 with batched int4 bucket loads: 8 gathers in flight per wave to hide
// L2/L3 latency (prev unroll-2 had only 2 -> VALUBusy 28%, latency-bound).

__global__ __launch_bounds__(256) void agg_kernel(const unsigned int* __restrict__ h2u,
                                                  const int* __restrict__ cnt,
                                                  const int2* __restrict__ bucket,
                                                  const float* __restrict__ dinv,
                                                  const float* __restrict__ b_conv,
                                                  const int* __restrict__ ovf_cnt,
                                                  const int4* __restrict__ ovf,
                                                  unsigned int* __restrict__ aggu, int n) {
    int idx = blockIdx.x * 256 + threadIdx.x;
    int node = idx >> 6;
    int lane = idx & 63;
    if (node >= n) return;
    int c = min(cnt[node], CAP);
    const int2* e = bucket + (size_t)node * CAP;   // 16B-aligned (node*640)

    unsigned self = h2u[(size_t)node * 64 + lane];
    float a0 = blo(self), a1 = bhi(self);          // acc pair A
    float b0 = 0.0f, b1 = 0.0f;                    // acc pair B (breaks FMA chain)

    int j = 0;
    for (; j + 8 <= c; j += 8) {
        int4 p0 = *(const int4*)(e + j);
        int4 p1 = *(const int4*)(e + j + 2);
        int4 p2 = *(const int4*)(e + j + 4);
        int4 p3 = *(const int4*)(e + j + 6);
        unsigned u0 = h2u[(size_t)p0.x * 64 + lane];
        unsigned u1 = h2u[(size_t)p0.z * 64 + lane];
        unsigned u2 = h2u[(size_t)p1.x * 64 + lane];
        unsigned u3 = h2u[(size_t)p1.z * 64 + lane];
        unsigned u4 = h2u[(size_t)p2.x * 64 + lane];
        unsigned u5 = h2u[(size_t)p2.z * 64 + lane];
        unsigned u6 = h2u[(size_t)p3.x * 64 + lane];
        unsigned u7 = h2u[(size_t)p3.z * 64 + lane];
        float w0 = __int_as_float(p0.y), w1 = __int_as_float(p0.w);
        float w2 = __int_as_float(p1.y), w3 = __int_as_float(p1.w);
        float w4 = __int_as_float(p2.y), w5 = __int_as_float(p2.w);
        float w6 = __int_as_float(p3.y), w7 = __int_as_float(p3.w);
        a0 += w0 * blo(u0); a1 += w0 * bhi(u0);
        b0 += w1 * blo(u1); b1 += w1 * bhi(u1);
        a0 += w2 * blo(u2); a1 += w2 * bhi(u2);
        b0 += w3 * blo(u3); b1 += w3 * bhi(u3);
        a0 += w4 * blo(u4); a1 += w4 * bhi(u4);
        b0 += w5 * blo(u5); b1 += w5 * bhi(u5);
        a0 += w6 * blo(u6); a1 += w6 * bhi(u6);
        b0 += w7 * blo(u7); b1 += w7 * bhi(u7);
    }
    for (; j + 2 <= c; j += 2) {
        int4 p = *(const int4*)(e + j);
        unsigned u0 = h2u[(size_t)p.x * 64 + lane];
        unsigned u1 = h2u[(size_t)p.z * 64 + lane];
        float w0 = __int_as_float(p.y), w1 = __int_as_float(p.w);
        a0 += w0 * blo(u0); a1 += w0 * bhi(u0);
        b0 += w1 * blo(u1); b1 += w1 * bhi(u1);
    }
    if (j < c) {
        int2 p = e[j];
        float w0 = __int_as_float(p.y);
        unsigned u0 = h2u[(size_t)p.x * 64 + lane];
        a0 += w0 * blo(u0); a1 += w0 * bhi(u0);
    }

    // overflow net (ovf_n is ~always 0)
    int ovf_n = min(*ovf_cnt, OVF_CAP);
    for (int i = 0; i < ovf_n; ++i) {
        int4 v = ovf[i];
        if (v.y == node) {
            float w0 = __int_as_float(v.z);
            unsigned u0 = h2u[(size_t)v.x * 64 + lane];
            a0 += w0 * blo(u0); a1 += w0 * bhi(u0);
        }
    }

    float di = dinv[node];
    float2 bc = *(const float2*)&b_conv[lane * 2];
    float v0 = bc.x + di * (a0 + b0);
    float v1 = bc.y + di * (a1 + b1);
    aggu[(size_t)node * 64 + lane] = (unsigned)f2bf(v0) | ((unsigned)f2bf(v1) << 16);
}

// ---------------- GEMM2: out[M,512](f32) = agg[M,128](bf16) @ Wl[128,512](f32) + b_lin ----

__global__ __launch_bounds__(256) void gemm2_kernel(const unsigned short* __restrict__ A,
                                                    const float* __restrict__ B,
                                                    const float* __restrict__ bias,
                                                    float* __restrict__ C,
                                                    int M) {
    __shared__ short As[128][40];
    __shared__ short Bs[128][40];
    const int bm = blockIdx.x * 128;
    const int bn = blockIdx.y * 128;
    const int tid = threadIdx.x;
    const int wave = tid >> 6, lane = tid & 63;
    const int wm = wave >> 1, wn = wave & 1;
    const int mlane = lane & 15, quad = lane >> 4;

    f32x4 acc[4][4];
#pragma unroll
    for (int i = 0; i < 4; ++i)
#pragma unroll
        for (int j = 0; j < 4; ++j) acc[i][j] = (f32x4){0.f, 0.f, 0.f, 0.f};

    for (int k0 = 0; k0 < HH; k0 += 32) {
        // A tile: 128 rows x 32 k bf16, direct copy. 512 16B tasks, 2/thread.
#pragma unroll
        for (int i = 0; i < 2; ++i) {
            int task = tid + i * 256;
            int row = task >> 2, ch = task & 3;
            int grow = bm + row;
            s16x8 v = (s16x8){0, 0, 0, 0, 0, 0, 0, 0};
            if (grow < M) v = *(const s16x8*)(A + (size_t)grow * HH + k0 + ch * 8);
            *(s16x8*)&As[row][ch * 8] = v;
        }
        // B tile: 32 k x 128 n fp32 -> bf16, transposed to [n][k].
#pragma unroll
        for (int i = 0; i < 2; ++i) {
            int task = tid + i * 256;
            int n = task & 127, kg = task >> 7;
            unsigned short tmp[8];
#pragma unroll
            for (int j = 0; j < 8; ++j)
                tmp[j] = f2bf(B[(size_t)(k0 + kg * 8 + j) * FIN + bn + n]);
            *(s16x8*)&Bs[n][kg * 8] = *(s16x8*)tmp;
        }
        __syncthreads();

        s16x8 af[4], bfr[4];
#pragma unroll
        for (int mt = 0; mt < 4; ++mt)
            af[mt] = *(const s16x8*)&As[wm * 64 + mt * 16 + mlane][quad * 8];
#pragma unroll
        for (int nt = 0; nt < 4; ++nt)
            bfr[nt] = *(const s16x8*)&Bs[wn * 64 + nt * 16 + mlane][quad * 8];
#pragma unroll
        for (int mt = 0; mt < 4; ++mt)
#pragma unroll
            for (int nt = 0; nt < 4; ++nt)
                acc[mt][nt] = __builtin_amdgcn_mfma_f32_16x16x32_bf16(af[mt], bfr[nt], acc[mt][nt], 0, 0, 0);
        __syncthreads();
    }

#pragma unroll
    for (int mt = 0; mt < 4; ++mt) {
#pragma unroll
        for (int r = 0; r < 4; ++r) {
            int row = bm + wm * 64 + mt * 16 + quad * 4 + r;
            if (row < M) {
#pragma unroll
                for (int nt = 0; nt < 4; ++nt) {
                    int col = bn + wn * 64 + nt * 16 + mlane;
                    C[(size_t)row * FIN + col] = acc[mt][nt][r] + bias[col];
                }
            }
        }
    }
}

// ---------------- launch ----------------

extern "C" void kernel_launch(void* const* d_in, const int* in_sizes, int n_in,
                              void* d_out, int out_size, void* d_ws, size_t ws_size,
                              hipStream_t stream) {
    const float* x      = (const float*)d_in[0];
    const int*   ei     = (const int*)d_in[1];
    const float* ew     = (const float*)d_in[2];
    const float* W_conv = (const float*)d_in[3];
    const float* b_conv = (const float*)d_in[4];
    const float* W_lin  = (const float*)d_in[5];
    const float* b_lin  = (const float*)d_in[6];
    float* out = (float*)d_out;

    const int* src = ei;
    const int* dst = ei + EE;

    // workspace layout (bytes, 256-aligned):
    char* ws = (char*)d_ws;
    int*            cnt      = (int*)           (ws + 0);          //   200,704
    float*          deg      = (float*)         (ws + 200704);     //   200,704
    float*          dinv     = (float*)         (ws + 401408);     //   200,704
    int*            ovf_cnt  = (int*)           (ws + 602112);     //       256
    int*            binTotal = (int*)           (ws + 602368);     //     1,792
    int*            binBase  = (int*)           (ws + 604160);     //     1,792
    int4*           ovf      = (int4*)          (ws + 605952);     // 1,032,192 (64512 entries) -> 1,638,144
    int2*           bucket   = (int2*)          (ws + 1650944);    // 32,000,000 -> 33,650,944
    unsigned short* h2       = (unsigned short*)(ws + 33650944);   // 12,800,000
    unsigned short* agg      = (unsigned short*)(ws + 46450944);   // 12,800,000
    // end: 59,250,944 bytes (unchanged footprint)

    // hist/off ALIAS the bucket region (dead until bucket_build writes bucket):
    int*            hist     = (int*)           (ws + 1650944);    //   400,640 (256*391*4)
    int*            off      = (int*)           (ws + 2051584);    //   400,640
    // bins ALIASES h2 (dead until gemm1): 1.6M * 8B = 12,800,000 exactly
    int2*           bins     = (int2*)          (ws + 33650944);

    hipMemsetAsync(ovf_cnt, 0, sizeof(int), stream);

    const int nb_n = (NN + 255) / 256;
    const int nb_w = (NN * 64 + 255) / 256;   // one wave per node

    // build: atomic-free counting sort by bin, then per-bin bucket build (LDS atomics)
    hist_kernel<<<NBLK, 256, 0, stream>>>(dst, hist);
    scan_bins<<<NB, 64, 0, stream>>>(hist, off, binTotal);
    bin_base<<<1, 512, 0, stream>>>(binTotal, binBase);
    place_kernel<<<NBLK, 256, 0, stream>>>(src, dst, ew, off, binBase, bins);
    bucket_build<<<NB, 512, 0, stream>>>(binBase, binTotal, bins, cnt, bucket, deg, ovf_cnt, ovf);
    ovf_deg<<<4, 256, 0, stream>>>(ovf_cnt, ovf, deg);
    dinv_kernel<<<nb_n, 256, 0, stream>>>(deg, dinv, NN);

    // GEMM1: h2 = bf16(dinv .* (x @ W_conv))
    gemm1_kernel<<<dim3((NN + 127) / 128, 1), 256, 0, stream>>>(x, W_conv, dinv, h2, NN);

    // aggregation (bf16 -> bf16)
    agg_kernel<<<nb_w, 256, 0, stream>>>((const unsigned int*)h2, cnt, bucket, dinv, b_conv,
                                         ovf_cnt, ovf, (unsigned int*)agg, NN);

    // GEMM2: out = agg @ W_lin + b_lin
    gemm2_kernel<<<dim3((NN + 127) / 128, FIN / 128), 256, 0, stream>>>(agg, W_lin, b_lin, out, NN);
}

// Round 5
// 353.979 us; speedup vs baseline: 1.4274x; 1.0565x over previous
//
#include <hip/hip_runtime.h>

// Problem constants (fixed by the reference)
#define NN 50000
#define EE 1600000
#define FIN 512
#define HH 128

#define CAP 80          // bucket capacity per dst (Poisson(32); P(deg>80) ~ 1e-11)
#define OVF_CAP 64512   // overflow list capacity (per-node CAP net, ~never used)

// counting-sort parameters
#define GROUP 128                        // nodes per bin
#define NB ((NN + GROUP - 1) / GROUP)    // 391 bins
#define NBLK 256                         // edge-chunk blocks
#define EPB (EE / NBLK)                  // 6250 edges per block (exact)

typedef short s16x8 __attribute__((ext_vector_type(8)));
typedef float f32x4 __attribute__((ext_vector_type(4)));

static __device__ inline unsigned short f2bf(float f) {
    // fp32 -> bf16 bits, round-to-nearest-even
    unsigned u = __float_as_uint(f);
    unsigned r = (u + 0x7fffu + ((u >> 16) & 1u)) >> 16;
    return (unsigned short)r;
}

static __device__ inline float blo(unsigned u) { return __uint_as_float(u << 16); }
static __device__ inline float bhi(unsigned u) { return __uint_as_float(u & 0xffff0000u); }

// ---------------- build kernels (atomic-free counting sort by bin) ----------------

// Pass 1: per-(block,bin) histogram via LDS atomics (block-local, cheap).
__global__ __launch_bounds__(256) void hist_kernel(const int* __restrict__ dst,
                                                   int* __restrict__ hist) {
    __shared__ int h[NB];
    const int tid = threadIdx.x;
    for (int i = tid; i < NB; i += 256) h[i] = 0;
    __syncthreads();
    const int base = blockIdx.x * EPB;
    for (int i = tid; i < EPB; i += 256)
        atomicAdd(&h[dst[base + i] >> 7], 1);
    __syncthreads();
    for (int i = tid; i < NB; i += 256) hist[blockIdx.x * NB + i] = h[i];
}

// Pass 2: one wave per bin — exclusive scan of hist[*][bin] over the 256 blocks.
__global__ __launch_bounds__(64) void scan_bins(const int* __restrict__ hist,
                                                int* __restrict__ off,
                                                int* __restrict__ binTotal) {
    const int bin = blockIdx.x;
    const int lane = threadIdx.x;
    int v[4];
    int s = 0;
#pragma unroll
    for (int i = 0; i < 4; ++i) { v[i] = hist[(lane * 4 + i) * NB + bin]; s += v[i]; }
    int incl = s;
#pragma unroll
    for (int d = 1; d < 64; d <<= 1) {
        int t = __shfl_up(incl, d, 64);
        if (lane >= d) incl += t;
    }
    int run = incl - s;   // exclusive prefix of this lane's 4 blocks
#pragma unroll
    for (int i = 0; i < 4; ++i) { off[(lane * 4 + i) * NB + bin] = run; run += v[i]; }
    if (lane == 63) binTotal[bin] = incl;
}

// Pass 3: exclusive scan over the 391 bin totals (single block).
__global__ __launch_bounds__(512) void bin_base(const int* __restrict__ binTotal,
                                                int* __restrict__ binBase) {
    __shared__ int s[512];
    const int t = threadIdx.x;
    int mine = (t < NB) ? binTotal[t] : 0;
    s[t] = mine;
    __syncthreads();
    for (int d = 1; d < 512; d <<= 1) {
        int v = (t >= d) ? s[t - d] : 0;
        __syncthreads();
        s[t] += v;
        __syncthreads();
    }
    if (t < NB) binBase[t] = s[t] - mine;   // exclusive
}

// Pass 4: deterministic placement. LDS cursors seeded from scanned offsets —
// zero global atomics; every bins[] slot written exactly once.
// Entry: x = src | (dstLocal<<16)  (src < 2^16, dstLocal < 128), y = w bits.
__global__ __launch_bounds__(256) void place_kernel(const int* __restrict__ src,
                                                    const int* __restrict__ dst,
                                                    const float* __restrict__ w,
                                                    const int* __restrict__ off,
                                                    const int* __restrict__ binBase,
                                                    int2* __restrict__ bins) {
    __shared__ int cur[NB];
    const int tid = threadIdx.x;
    for (int i = tid; i < NB; i += 256)
        cur[i] = binBase[i] + off[blockIdx.x * NB + i];
    __syncthreads();
    const int base = blockIdx.x * EPB;
    for (int i = tid; i < EPB; i += 256) {
        int e = base + i;
        int s = src[e], d = dst[e];
        float we = w[e];
        int pos = atomicAdd(&cur[d >> 7], 1);
        bins[pos] = make_int2(s | ((d & 127) << 16), __float_as_int(we));
    }
}

// Pass 5: one block per bin. Scatter entries into per-node buckets (80KB window
// per bin, L2-resident). Per-node positions and weight sums via LDS atomics.
// Also writes cnt[] and deg[].
__global__ __launch_bounds__(512) void bucket_build(const int* __restrict__ binBase,
                                                    const int* __restrict__ binTotal,
                                                    const int2* __restrict__ bins,
                                                    int* __restrict__ cnt,
                                                    int2* __restrict__ bucket,
                                                    float* __restrict__ deg,
                                                    int* __restrict__ ovf_cnt,
                                                    int4* __restrict__ ovf) {
    __shared__ int lcnt[GROUP];
    __shared__ float lw[GROUP];
    const int b = blockIdx.x;
    const int tid = threadIdx.x;
    if (tid < GROUP) { lcnt[tid] = 0; lw[tid] = 0.0f; }
    __syncthreads();
    const int base = b * GROUP;
    const int start = binBase[b];
    const int n = binTotal[b];
    for (int i = tid; i < n; i += 512) {
        int2 en = bins[start + i];
        int sr = en.x & 0xffff;
        int dl = (en.x >> 16) & 127;
        int pos = atomicAdd(&lcnt[dl], 1);
        if (pos < CAP) {
            bucket[(size_t)(base + dl) * CAP + pos] = make_int2(sr, en.y);
            atomicAdd(&lw[dl], __int_as_float(en.y));
        } else {
            // node exceeded CAP: divert to overflow net (deg via ovf_deg)
            int o = atomicAdd(ovf_cnt, 1);
            if (o < OVF_CAP) ovf[o] = make_int4(sr, base + dl, en.y, 0);
        }
    }
    __syncthreads();
    for (int i = tid; i < GROUP; i += 512) {
        int node = base + i;
        if (node < NN) {
            cnt[node] = lcnt[i];                 // raw; consumers do min(cnt, CAP)
            deg[node] = 1.0f + lw[i];            // self-loop + bucketed weights
        }
    }
}

__global__ void ovf_deg(const int* __restrict__ ovf_cnt, const int4* __restrict__ ovf,
                        float* __restrict__ deg) {
    int n = min(*ovf_cnt, OVF_CAP);
    for (int i = blockIdx.x * blockDim.x + threadIdx.x; i < n; i += blockDim.x * gridDim.x)
        atomicAdd(deg + ovf[i].y, __int_as_float(ovf[i].z));
}

__global__ void dinv_kernel(const float* __restrict__ deg, float* __restrict__ dinv, int n) {
    int i = blockIdx.x * 256 + threadIdx.x;
    if (i < n) {
        float d = deg[i];
        dinv[i] = (d > 0.0f) ? rsqrtf(d) : 0.0f;
    }
}

// ---------------- GEMM1: h2[M,128](bf16) = dinv .* (x[M,512](f32) @ Wc[512,128](f32)) ----
// Memory-bound (57 FLOP/B): the job is streaming x at HBM rate. 512 threads (8 waves,
// 4x2) double waves/CU at the grid-limited 391 blocks; 2-deep register prefetch
// (issue loads for k+2 during MFMA of k, write-late after the barrier) hides HBM
// latency across two K-iterations instead of zero.

__global__ __launch_bounds__(512) void gemm1_kernel(const float* __restrict__ A,
                                                    const float* __restrict__ B,
                                                    const float* __restrict__ dinv,
                                                    unsigned short* __restrict__ h2,
                                                    int M) {
    __shared__ short As[128][40];   // [m][k], pad to 40 (80B rows)
    __shared__ short Bs[128][40];   // [n][k]
    const int bm = blockIdx.x * 128;
    const int tid = threadIdx.x;
    const int wave = tid >> 6, lane = tid & 63;
    const int wm = wave >> 1, wn = wave & 1;        // 4x2 wave grid: 32-row x 64-col per wave
    const int mlane = lane & 15, quad = lane >> 4;

    // staging geometry: A = 1024 float4 tasks -> 2/thread; B = 512 (n,kg) tasks -> 1/thread
    const int ar = tid >> 3, akq = tid & 7;          // A rows ar and ar+64
    const int bn = tid & 127, bkg = tid >> 7;        // B col bn, k-group bkg (0..3)

    f32x4 acc[2][4];
#pragma unroll
    for (int i = 0; i < 2; ++i)
#pragma unroll
        for (int j = 0; j < 4; ++j) acc[i][j] = (f32x4){0.f, 0.f, 0.f, 0.f};

    float4 pa0[2], pa1[2];
    float pb0[8], pb1[8];

    auto loadT = [&](float4 (&pa)[2], float (&pb)[8], int k0) {
#pragma unroll
        for (int i = 0; i < 2; ++i) {
            int grow = bm + ar + i * 64;
            pa[i] = make_float4(0.f, 0.f, 0.f, 0.f);
            if (grow < M) pa[i] = *(const float4*)(A + (size_t)grow * FIN + k0 + akq * 4);
        }
#pragma unroll
        for (int j = 0; j < 8; ++j)
            pb[j] = B[(size_t)(k0 + bkg * 8 + j) * HH + bn];
    };
    auto storeT = [&](float4 (&pa)[2], float (&pb)[8]) {
#pragma unroll
        for (int i = 0; i < 2; ++i) {
            ushort4 b;
            b.x = f2bf(pa[i].x); b.y = f2bf(pa[i].y); b.z = f2bf(pa[i].z); b.w = f2bf(pa[i].w);
            *(ushort4*)&As[ar + i * 64][akq * 4] = b;
        }
        unsigned short tmp[8];
#pragma unroll
        for (int j = 0; j < 8; ++j) tmp[j] = f2bf(pb[j]);
        *(s16x8*)&Bs[bn][bkg * 8] = *(s16x8*)tmp;
    };
    auto mmaT = [&]() {
        s16x8 af[2], bfr[4];
#pragma unroll
        for (int mt = 0; mt < 2; ++mt)
            af[mt] = *(const s16x8*)&As[wm * 32 + mt * 16 + mlane][quad * 8];
#pragma unroll
        for (int nt = 0; nt < 4; ++nt)
            bfr[nt] = *(const s16x8*)&Bs[wn * 64 + nt * 16 + mlane][quad * 8];
#pragma unroll
        for (int mt = 0; mt < 2; ++mt)
#pragma unroll
            for (int nt = 0; nt < 4; ++nt)
                acc[mt][nt] = __builtin_amdgcn_mfma_f32_16x16x32_bf16(af[mt], bfr[nt], acc[mt][nt], 0, 0, 0);
    };

    // 2-deep pipeline over 16 K-steps (named regs -> no dynamic indexing/scratch)
    loadT(pa0, pb0, 0);
    loadT(pa1, pb1, 32);
    for (int kk = 0; kk < 16; kk += 2) {
        storeT(pa0, pb0);               // waits only on loads issued 2 iters ago
        __syncthreads();
        if (kk + 2 < 16) loadT(pa0, pb0, (kk + 2) * 32);
        mmaT();
        __syncthreads();
        storeT(pa1, pb1);
        __syncthreads();
        if (kk + 3 < 16) loadT(pa1, pb1, (kk + 3) * 32);
        mmaT();
        __syncthreads();
    }

    // epilogue: D[row=quad*4+r][col=lane&15] per frag; scale by dinv, store bf16
#pragma unroll
    for (int mt = 0; mt < 2; ++mt) {
#pragma unroll
        for (int r = 0; r < 4; ++r) {
            int row = bm + wm * 32 + mt * 16 + quad * 4 + r;
            if (row < M) {
                float sc = dinv[row];
#pragma unroll
                for (int nt = 0; nt < 4; ++nt) {
                    int col = wn * 64 + nt * 16 + mlane;
                    h2[(size_t)row * HH + col] = f2bf(acc[mt][nt][r] * sc);
                }
            }
        }
    }
}

// ---------------- aggregation (bf16 in / bf16 out) ----------------
// agg[d] = bf16( b_conv + dinv[d] * (h2[d] + sum_e w_e * h2[src_e]) )
// one 64-lane wave per node; each lane owns feature pair (2*lane, 2*lane+1) as packed uint.
// Unroll-8 with batched int4 bucket loads: 8 gathers in flight per wave to hide
// L2/L3 latency (prev unroll-2 had only 2 -> VALUBusy 28%, latency-bound).

__global__ __launch_bounds__(256) void agg_kernel(const unsigned int* __restrict__ h2u,
                                                  const int* __restrict__ cnt,
                                                  const int2* __restrict__ bucket,
                                                  const float* __restrict__ dinv,
                                                  const float* __restrict__ b_conv,
                                                  const int* __restrict__ ovf_cnt,
                                                  const int4* __restrict__ ovf,
                                                  unsigned int* __restrict__ aggu, int n) {
    int idx = blockIdx.x * 256 + threadIdx.x;
    int node = idx >> 6;
    int lane = idx & 63;
    if (node >= n) return;
    int c = min(cnt[node], CAP);
    const int2* e = bucket + (size_t)node * CAP;   // 16B-aligned (node*640)

    unsigned self = h2u[(size_t)node * 64 + lane];
    float a0 = blo(self), a1 = bhi(self);          // acc pair A
    float b0 = 0.0f, b1 = 0.0f;                    // acc pair B (breaks FMA chain)

    int j = 0;
    for (; j + 8 <= c; j += 8) {
        int4 p0 = *(const int4*)(e + j);
        int4 p1 = *(const int4*)(e + j + 2);
        int4 p2 = *(const int4*)(e + j + 4);
        int4 p3 = *(const int4*)(e + j + 6);
        unsigned u0 = h2u[(size_t)p0.x * 64 + lane];
        unsigned u1 = h2u[(size_t)p0.z * 64 + lane];
        unsigned u2 = h2u[(size_t)p1.x * 64 + lane];
        unsigned u3 = h2u[(size_t)p1.z * 64 + lane];
        unsigned u4 = h2u[(size_t)p2.x * 64 + lane];
        unsigned u5 = h2u[(size_t)p2.z * 64 + lane];
        unsigned u6 = h2u[(size_t)p3.x * 64 + lane];
        unsigned u7 = h2u[(size_t)p3.z * 64 + lane];
        float w0 = __int_as_float(p0.y), w1 = __int_as_float(p0.w);
        float w2 = __int_as_float(p1.y), w3 = __int_as_float(p1.w);
        float w4 = __int_as_float(p2.y), w5 = __int_as_float(p2.w);
        float w6 = __int_as_float(p3.y), w7 = __int_as_float(p3.w);
        a0 += w0 * blo(u0); a1 += w0 * bhi(u0);
        b0 += w1 * blo(u1); b1 += w1 * bhi(u1);
        a0 += w2 * blo(u2); a1 += w2 * bhi(u2);
        b0 += w3 * blo(u3); b1 += w3 * bhi(u3);
        a0 += w4 * blo(u4); a1 += w4 * bhi(u4);
        b0 += w5 * blo(u5); b1 += w5 * bhi(u5);
        a0 += w6 * blo(u6); a1 += w6 * bhi(u6);
        b0 += w7 * blo(u7); b1 += w7 * bhi(u7);
    }
    for (; j + 2 <= c; j += 2) {
        int4 p = *(const int4*)(e + j);
        unsigned u0 = h2u[(size_t)p.x * 64 + lane];
        unsigned u1 = h2u[(size_t)p.z * 64 + lane];
        float w0 = __int_as_float(p.y), w1 = __int_as_float(p.w);
        a0 += w0 * blo(u0); a1 += w0 * bhi(u0);
        b0 += w1 * blo(u1); b1 += w1 * bhi(u1);
    }
    if (j < c) {
        int2 p = e[j];
        float w0 = __int_as_float(p.y);
        unsigned u0 = h2u[(size_t)p.x * 64 + lane];
        a0 += w0 * blo(u0); a1 += w0 * bhi(u0);
    }

    // overflow net (ovf_n is ~always 0)
    int ovf_n = min(*ovf_cnt, OVF_CAP);
    for (int i = 0; i < ovf_n; ++i) {
        int4 v = ovf[i];
        if (v.y == node) {
            float w0 = __int_as_float(v.z);
            unsigned u0 = h2u[(size_t)v.x * 64 + lane];
            a0 += w0 * blo(u0); a1 += w0 * bhi(u0);
        }
    }

    float di = dinv[node];
    float2 bc = *(const float2*)&b_conv[lane * 2];
    float v0 = bc.x + di * (a0 + b0);
    float v1 = bc.y + di * (a1 + b1);
    aggu[(size_t)node * 64 + lane] = (unsigned)f2bf(v0) | ((unsigned)f2bf(v1) << 16);
}

// ---------------- GEMM2: out[M,512](f32) = agg[M,128](bf16) @ Wl[128,512](f32) + b_lin ----

__global__ __launch_bounds__(256) void gemm2_kernel(const unsigned short* __restrict__ A,
                                                    const float* __restrict__ B,
                                                    const float* __restrict__ bias,
                                                    float* __restrict__ C,
                                                    int M) {
    __shared__ short As[128][40];
    __shared__ short Bs[128][40];
    const int bm = blockIdx.x * 128;
    const int bn = blockIdx.y * 128;
    const int tid = threadIdx.x;
    const int wave = tid >> 6, lane = tid & 63;
    const int wm = wave >> 1, wn = wave & 1;
    const int mlane = lane & 15, quad = lane >> 4;

    f32x4 acc[4][4];
#pragma unroll
    for (int i = 0; i < 4; ++i)
#pragma unroll
        for (int j = 0; j < 4; ++j) acc[i][j] = (f32x4){0.f, 0.f, 0.f, 0.f};

    for (int k0 = 0; k0 < HH; k0 += 32) {
        // A tile: 128 rows x 32 k bf16, direct copy. 512 16B tasks, 2/thread.
#pragma unroll
        for (int i = 0; i < 2; ++i) {
            int task = tid + i * 256;
            int row = task >> 2, ch = task & 3;
            int grow = bm + row;
            s16x8 v = (s16x8){0, 0, 0, 0, 0, 0, 0, 0};
            if (grow < M) v = *(const s16x8*)(A + (size_t)grow * HH + k0 + ch * 8);
            *(s16x8*)&As[row][ch * 8] = v;
        }
        // B tile: 32 k x 128 n fp32 -> bf16, transposed to [n][k].
#pragma unroll
        for (int i = 0; i < 2; ++i) {
            int task = tid + i * 256;
            int n = task & 127, kg = task >> 7;
            unsigned short tmp[8];
#pragma unroll
            for (int j = 0; j < 8; ++j)
                tmp[j] = f2bf(B[(size_t)(k0 + kg * 8 + j) * FIN + bn + n]);
            *(s16x8*)&Bs[n][kg * 8] = *(s16x8*)tmp;
        }
        __syncthreads();

        s16x8 af[4], bfr[4];
#pragma unroll
        for (int mt = 0; mt < 4; ++mt)
            af[mt] = *(const s16x8*)&As[wm * 64 + mt * 16 + mlane][quad * 8];
#pragma unroll
        for (int nt = 0; nt < 4; ++nt)
            bfr[nt] = *(const s16x8*)&Bs[wn * 64 + nt * 16 + mlane][quad * 8];
#pragma unroll
        for (int mt = 0; mt < 4; ++mt)
#pragma unroll
            for (int nt = 0; nt < 4; ++nt)
                acc[mt][nt] = __builtin_amdgcn_mfma_f32_16x16x32_bf16(af[mt], bfr[nt], acc[mt][nt], 0, 0, 0);
        __syncthreads();
    }

#pragma unroll
    for (int mt = 0; mt < 4; ++mt) {
#pragma unroll
        for (int r = 0; r < 4; ++r) {
            int row = bm + wm * 64 + mt * 16 + quad * 4 + r;
            if (row < M) {
#pragma unroll
                for (int nt = 0; nt < 4; ++nt) {
                    int col = bn + wn * 64 + nt * 16 + mlane;
                    C[(size_t)row * FIN + col] = acc[mt][nt][r] + bias[col];
                }
            }
        }
    }
}

// ---------------- launch ----------------

extern "C" void kernel_launch(void* const* d_in, const int* in_sizes, int n_in,
                              void* d_out, int out_size, void* d_ws, size_t ws_size,
                              hipStream_t stream) {
    const float* x      = (const float*)d_in[0];
    const int*   ei     = (const int*)d_in[1];
    const float* ew     = (const float*)d_in[2];
    const float* W_conv = (const float*)d_in[3];
    const float* b_conv = (const float*)d_in[4];
    const float* W_lin  = (const float*)d_in[5];
    const float* b_lin  = (const float*)d_in[6];
    float* out = (float*)d_out;

    const int* src = ei;
    const int* dst = ei + EE;

    // workspace layout (bytes, 256-aligned):
    char* ws = (char*)d_ws;
    int*            cnt      = (int*)           (ws + 0);          //   200,704
    float*          deg      = (float*)         (ws + 200704);     //   200,704
    float*          dinv     = (float*)         (ws + 401408);     //   200,704
    int*            ovf_cnt  = (int*)           (ws + 602112);     //       256
    int*            binTotal = (int*)           (ws + 602368);     //     1,792
    int*            binBase  = (int*)           (ws + 604160);     //     1,792
    int4*           ovf      = (int4*)          (ws + 605952);     // 1,032,192 (64512 entries) -> 1,638,144
    int2*           bucket   = (int2*)          (ws + 1650944);    // 32,000,000 -> 33,650,944
    unsigned short* h2       = (unsigned short*)(ws + 33650944);   // 12,800,000
    unsigned short* agg      = (unsigned short*)(ws + 46450944);   // 12,800,000
    // end: 59,250,944 bytes (unchanged footprint)

    // hist/off ALIAS the bucket region (dead until bucket_build writes bucket):
    int*            hist     = (int*)           (ws + 1650944);    //   400,640 (256*391*4)
    int*            off      = (int*)           (ws + 2051584);    //   400,640
    // bins ALIASES h2 (dead until gemm1): 1.6M * 8B = 12,800,000 exactly
    int2*           bins     = (int2*)          (ws + 33650944);

    hipMemsetAsync(ovf_cnt, 0, sizeof(int), stream);

    const int nb_n = (NN + 255) / 256;
    const int nb_w = (NN * 64 + 255) / 256;   // one wave per node

    // build: atomic-free counting sort by bin, then per-bin bucket build (LDS atomics)
    hist_kernel<<<NBLK, 256, 0, stream>>>(dst, hist);
    scan_bins<<<NB, 64, 0, stream>>>(hist, off, binTotal);
    bin_base<<<1, 512, 0, stream>>>(binTotal, binBase);
    place_kernel<<<NBLK, 256, 0, stream>>>(src, dst, ew, off, binBase, bins);
    bucket_build<<<NB, 512, 0, stream>>>(binBase, binTotal, bins, cnt, bucket, deg, ovf_cnt, ovf);
    ovf_deg<<<4, 256, 0, stream>>>(ovf_cnt, ovf, deg);
    dinv_kernel<<<nb_n, 256, 0, stream>>>(deg, dinv, NN);

    // GEMM1: h2 = bf16(dinv .* (x @ W_conv))
    gemm1_kernel<<<dim3((NN + 127) / 128, 1), 512, 0, stream>>>(x, W_conv, dinv, h2, NN);

    // aggregation (bf16 -> bf16)
    agg_kernel<<<nb_w, 256, 0, stream>>>((const unsigned int*)h2, cnt, bucket, dinv, b_conv,
                                         ovf_cnt, ovf, (unsigned int*)agg, NN);

    // GEMM2: out = agg @ W_lin + b_lin
    gemm2_kernel<<<dim3((NN + 127) / 128, FIN / 128), 256, 0, stream>>>(agg, W_lin, b_lin, out, NN);
}

// Round 6
// 349.067 us; speedup vs baseline: 1.4475x; 1.0141x over previous
//
#include <hip/hip_runtime.h>

// Problem constants (fixed by the reference)
#define NN 50000
#define EE 1600000
#define FIN 512
#define HH 128

#define CAP 80          // bucket capacity per dst (Poisson(32); P(deg>80) ~ 1e-11)
#define OVF_CAP 64512   // overflow list capacity (per-node CAP net, ~never used)

// counting-sort parameters
#define GROUP 128                        // nodes per bin
#define NB ((NN + GROUP - 1) / GROUP)    // 391 bins
#define NBLK 256                         // edge-chunk blocks
#define EPB (EE / NBLK)                  // 6250 edges per block (exact)

typedef short s16x8 __attribute__((ext_vector_type(8)));
typedef float f32x4 __attribute__((ext_vector_type(4)));

static __device__ inline unsigned short f2bf(float f) {
    // fp32 -> bf16 bits, round-to-nearest-even
    unsigned u = __float_as_uint(f);
    unsigned r = (u + 0x7fffu + ((u >> 16) & 1u)) >> 16;
    return (unsigned short)r;
}

static __device__ inline float blo(unsigned u) { return __uint_as_float(u << 16); }
static __device__ inline float bhi(unsigned u) { return __uint_as_float(u & 0xffff0000u); }

static __device__ inline float deg2dinv(float d) { return (d > 0.0f) ? rsqrtf(d) : 0.0f; }

// ---------------- build kernels (atomic-free counting sort by bin) ----------------

// Pass 1: per-(block,bin) histogram via LDS atomics (block-local, cheap).
__global__ __launch_bounds__(256) void hist_kernel(const int* __restrict__ dst,
                                                   int* __restrict__ hist) {
    __shared__ int h[NB];
    const int tid = threadIdx.x;
    for (int i = tid; i < NB; i += 256) h[i] = 0;
    __syncthreads();
    const int base = blockIdx.x * EPB;
    for (int i = tid; i < EPB; i += 256)
        atomicAdd(&h[dst[base + i] >> 7], 1);
    __syncthreads();
    for (int i = tid; i < NB; i += 256) hist[blockIdx.x * NB + i] = h[i];
}

// Pass 2: one wave per bin — exclusive scan of hist[*][bin] over the 256 blocks.
__global__ __launch_bounds__(64) void scan_bins(const int* __restrict__ hist,
                                                int* __restrict__ off,
                                                int* __restrict__ binTotal) {
    const int bin = blockIdx.x;
    const int lane = threadIdx.x;
    int v[4];
    int s = 0;
#pragma unroll
    for (int i = 0; i < 4; ++i) { v[i] = hist[(lane * 4 + i) * NB + bin]; s += v[i]; }
    int incl = s;
#pragma unroll
    for (int d = 1; d < 64; d <<= 1) {
        int t = __shfl_up(incl, d, 64);
        if (lane >= d) incl += t;
    }
    int run = incl - s;   // exclusive prefix of this lane's 4 blocks
#pragma unroll
    for (int i = 0; i < 4; ++i) { off[(lane * 4 + i) * NB + bin] = run; run += v[i]; }
    if (lane == 63) binTotal[bin] = incl;
}

// Pass 3: exclusive scan over the 391 bin totals (single block).
__global__ __launch_bounds__(512) void bin_base(const int* __restrict__ binTotal,
                                                int* __restrict__ binBase) {
    __shared__ int s[512];
    const int t = threadIdx.x;
    int mine = (t < NB) ? binTotal[t] : 0;
    s[t] = mine;
    __syncthreads();
    for (int d = 1; d < 512; d <<= 1) {
        int v = (t >= d) ? s[t - d] : 0;
        __syncthreads();
        s[t] += v;
        __syncthreads();
    }
    if (t < NB) binBase[t] = s[t] - mine;   // exclusive
}

// Pass 4: deterministic placement. LDS cursors seeded from scanned offsets —
// zero global atomics; every bins[] slot written exactly once.
// Entry: x = src | (dstLocal<<16)  (src < 2^16, dstLocal < 128), y = w bits.
__global__ __launch_bounds__(256) void place_kernel(const int* __restrict__ src,
                                                    const int* __restrict__ dst,
                                                    const float* __restrict__ w,
                                                    const int* __restrict__ off,
                                                    const int* __restrict__ binBase,
                                                    int2* __restrict__ bins) {
    __shared__ int cur[NB];
    const int tid = threadIdx.x;
    for (int i = tid; i < NB; i += 256)
        cur[i] = binBase[i] + off[blockIdx.x * NB + i];
    __syncthreads();
    const int base = blockIdx.x * EPB;
    for (int i = tid; i < EPB; i += 256) {
        int e = base + i;
        int s = src[e], d = dst[e];
        float we = w[e];
        int pos = atomicAdd(&cur[d >> 7], 1);
        bins[pos] = make_int2(s | ((d & 127) << 16), __float_as_int(we));
    }
}

// Pass 5: one block per bin. Scatter entries into per-node buckets (80KB window
// per bin, L2-resident). Per-node positions and weight sums via LDS atomics.
// Also writes cnt[] and deg[].
__global__ __launch_bounds__(512) void bucket_build(const int* __restrict__ binBase,
                                                    const int* __restrict__ binTotal,
                                                    const int2* __restrict__ bins,
                                                    int* __restrict__ cnt,
                                                    int2* __restrict__ bucket,
                                                    float* __restrict__ deg,
                                                    int* __restrict__ ovf_cnt,
                                                    int4* __restrict__ ovf) {
    __shared__ int lcnt[GROUP];
    __shared__ float lw[GROUP];
    const int b = blockIdx.x;
    const int tid = threadIdx.x;
    if (tid < GROUP) { lcnt[tid] = 0; lw[tid] = 0.0f; }
    __syncthreads();
    const int base = b * GROUP;
    const int start = binBase[b];
    const int n = binTotal[b];
    for (int i = tid; i < n; i += 512) {
        int2 en = bins[start + i];
        int sr = en.x & 0xffff;
        int dl = (en.x >> 16) & 127;
        int pos = atomicAdd(&lcnt[dl], 1);
        if (pos < CAP) {
            bucket[(size_t)(base + dl) * CAP + pos] = make_int2(sr, en.y);
            atomicAdd(&lw[dl], __int_as_float(en.y));
        } else {
            // node exceeded CAP: divert to overflow net (deg via ovf_deg)
            int o = atomicAdd(ovf_cnt, 1);
            if (o < OVF_CAP) ovf[o] = make_int4(sr, base + dl, en.y, 0);
        }
    }
    __syncthreads();
    for (int i = tid; i < GROUP; i += 512) {
        int node = base + i;
        if (node < NN) {
            cnt[node] = lcnt[i];                 // raw; consumers do min(cnt, CAP)
            deg[node] = 1.0f + lw[i];            // self-loop + bucketed weights
        }
    }
}

__global__ void ovf_deg(const int* __restrict__ ovf_cnt, const int4* __restrict__ ovf,
                        float* __restrict__ deg) {
    int n = min(*ovf_cnt, OVF_CAP);
    for (int i = blockIdx.x * blockDim.x + threadIdx.x; i < n; i += blockDim.x * gridDim.x)
        atomicAdd(deg + ovf[i].y, __int_as_float(ovf[i].z));
}

// ---------------- GEMM1: h2[M,128](bf16) = dinv .* (x[M,512](f32) @ Wc[512,128](f32)) ----
// Memory-bound (57 FLOP/B). 512 threads (8 waves, 4x2); 2-deep register prefetch
// (issue loads for k+2 during MFMA of k, write-late after the barrier) hides HBM
// latency across two K-iterations. dinv computed inline from deg (kills a launch).

__global__ __launch_bounds__(512) void gemm1_kernel(const float* __restrict__ A,
                                                    const float* __restrict__ B,
                                                    const float* __restrict__ deg,
                                                    unsigned short* __restrict__ h2,
                                                    int M) {
    __shared__ short As[128][40];   // [m][k], pad to 40 (80B rows)
    __shared__ short Bs[128][40];   // [n][k]
    const int bm = blockIdx.x * 128;
    const int tid = threadIdx.x;
    const int wave = tid >> 6, lane = tid & 63;
    const int wm = wave >> 1, wn = wave & 1;        // 4x2 wave grid: 32-row x 64-col per wave
    const int mlane = lane & 15, quad = lane >> 4;

    // staging geometry: A = 1024 float4 tasks -> 2/thread; B = 512 (n,kg) tasks -> 1/thread
    const int ar = tid >> 3, akq = tid & 7;          // A rows ar and ar+64
    const int bn = tid & 127, bkg = tid >> 7;        // B col bn, k-group bkg (0..3)

    f32x4 acc[2][4];
#pragma unroll
    for (int i = 0; i < 2; ++i)
#pragma unroll
        for (int j = 0; j < 4; ++j) acc[i][j] = (f32x4){0.f, 0.f, 0.f, 0.f};

    float4 pa0[2], pa1[2];
    float pb0[8], pb1[8];

    auto loadT = [&](float4 (&pa)[2], float (&pb)[8], int k0) {
#pragma unroll
        for (int i = 0; i < 2; ++i) {
            int grow = bm + ar + i * 64;
            pa[i] = make_float4(0.f, 0.f, 0.f, 0.f);
            if (grow < M) pa[i] = *(const float4*)(A + (size_t)grow * FIN + k0 + akq * 4);
        }
#pragma unroll
        for (int j = 0; j < 8; ++j)
            pb[j] = B[(size_t)(k0 + bkg * 8 + j) * HH + bn];
    };
    auto storeT = [&](float4 (&pa)[2], float (&pb)[8]) {
#pragma unroll
        for (int i = 0; i < 2; ++i) {
            ushort4 b;
            b.x = f2bf(pa[i].x); b.y = f2bf(pa[i].y); b.z = f2bf(pa[i].z); b.w = f2bf(pa[i].w);
            *(ushort4*)&As[ar + i * 64][akq * 4] = b;
        }
        unsigned short tmp[8];
#pragma unroll
        for (int j = 0; j < 8; ++j) tmp[j] = f2bf(pb[j]);
        *(s16x8*)&Bs[bn][bkg * 8] = *(s16x8*)tmp;
    };
    auto mmaT = [&]() {
        s16x8 af[2], bfr[4];
#pragma unroll
        for (int mt = 0; mt < 2; ++mt)
            af[mt] = *(const s16x8*)&As[wm * 32 + mt * 16 + mlane][quad * 8];
#pragma unroll
        for (int nt = 0; nt < 4; ++nt)
            bfr[nt] = *(const s16x8*)&Bs[wn * 64 + nt * 16 + mlane][quad * 8];
#pragma unroll
        for (int mt = 0; mt < 2; ++mt)
#pragma unroll
            for (int nt = 0; nt < 4; ++nt)
                acc[mt][nt] = __builtin_amdgcn_mfma_f32_16x16x32_bf16(af[mt], bfr[nt], acc[mt][nt], 0, 0, 0);
    };

    // 2-deep pipeline over 16 K-steps (named regs -> no dynamic indexing/scratch)
    loadT(pa0, pb0, 0);
    loadT(pa1, pb1, 32);
    for (int kk = 0; kk < 16; kk += 2) {
        storeT(pa0, pb0);               // waits only on loads issued 2 iters ago
        __syncthreads();
        if (kk + 2 < 16) loadT(pa0, pb0, (kk + 2) * 32);
        mmaT();
        __syncthreads();
        storeT(pa1, pb1);
        __syncthreads();
        if (kk + 3 < 16) loadT(pa1, pb1, (kk + 3) * 32);
        mmaT();
        __syncthreads();
    }

    // epilogue: D[row=quad*4+r][col=lane&15] per frag; scale by dinv(deg), store bf16
#pragma unroll
    for (int mt = 0; mt < 2; ++mt) {
#pragma unroll
        for (int r = 0; r < 4; ++r) {
            int row = bm + wm * 32 + mt * 16 + quad * 4 + r;
            if (row < M) {
                float sc = deg2dinv(deg[row]);
#pragma unroll
                for (int nt = 0; nt < 4; ++nt) {
                    int col = wn * 64 + nt * 16 + mlane;
                    h2[(size_t)row * HH + col] = f2bf(acc[mt][nt][r] * sc);
                }
            }
        }
    }
}

// ---------------- aggregation (bf16 in / bf16 out) ----------------
// agg[d] = bf16( b_conv + dinv[d] * (h2[d] + sum_e w_e * h2[src_e]) )
// one 64-lane wave per node; each lane owns feature pair (2*lane, 2*lane+1) as packed uint.
// Unroll-8 with batched int4 bucket loads: 8 gathers in flight per wave to hide
// L2/L3 latency (prev unroll-2 had only 2 -> VALUBusy 28%, latency-bound).

__global__ __launch_bounds__(256) void agg_kernel(const unsigned int* __restrict__ h2u,
                                                  const int* __restrict__ cnt,
                                                  const int2* __restrict__ bucket,
                                                  const float* __restrict__ deg,
                                                  const float* __restrict__ b_conv,
                                                  const int* __restrict__ ovf_cnt,
                                                  const int4* __restrict__ ovf,
                                                  unsigned int* __restrict__ aggu, int n) {
    int idx = blockIdx.x * 256 + threadIdx.x;
    int node = idx >> 6;
    int lane = idx & 63;
    if (node >= n) return;
    int c = min(cnt[node], CAP);
    const int2* e = bucket + (size_t)node * CAP;   // 16B-aligned (node*640)

    unsigned self = h2u[(size_t)node * 64 + lane];
    float a0 = blo(self), a1 = bhi(self);          // acc pair A
    float b0 = 0.0f, b1 = 0.0f;                    // acc pair B (breaks FMA chain)

    int j = 0;
    for (; j + 8 <= c; j += 8) {
        int4 p0 = *(const int4*)(e + j);
        int4 p1 = *(const int4*)(e + j + 2);
        int4 p2 = *(const int4*)(e + j + 4);
        int4 p3 = *(const int4*)(e + j + 6);
        unsigned u0 = h2u[(size_t)p0.x * 64 + lane];
        unsigned u1 = h2u[(size_t)p0.z * 64 + lane];
        unsigned u2 = h2u[(size_t)p1.x * 64 + lane];
        unsigned u3 = h2u[(size_t)p1.z * 64 + lane];
        unsigned u4 = h2u[(size_t)p2.x * 64 + lane];
        unsigned u5 = h2u[(size_t)p2.z * 64 + lane];
        unsigned u6 = h2u[(size_t)p3.x * 64 + lane];
        unsigned u7 = h2u[(size_t)p3.z * 64 + lane];
        float w0 = __int_as_float(p0.y), w1 = __int_as_float(p0.w);
        float w2 = __int_as_float(p1.y), w3 = __int_as_float(p1.w);
        float w4 = __int_as_float(p2.y), w5 = __int_as_float(p2.w);
        float w6 = __int_as_float(p3.y), w7 = __int_as_float(p3.w);
        a0 += w0 * blo(u0); a1 += w0 * bhi(u0);
        b0 += w1 * blo(u1); b1 += w1 * bhi(u1);
        a0 += w2 * blo(u2); a1 += w2 * bhi(u2);
        b0 += w3 * blo(u3); b1 += w3 * bhi(u3);
        a0 += w4 * blo(u4); a1 += w4 * bhi(u4);
        b0 += w5 * blo(u5); b1 += w5 * bhi(u5);
        a0 += w6 * blo(u6); a1 += w6 * bhi(u6);
        b0 += w7 * blo(u7); b1 += w7 * bhi(u7);
    }
    for (; j + 2 <= c; j += 2) {
        int4 p = *(const int4*)(e + j);
        unsigned u0 = h2u[(size_t)p.x * 64 + lane];
        unsigned u1 = h2u[(size_t)p.z * 64 + lane];
        float w0 = __int_as_float(p.y), w1 = __int_as_float(p.w);
        a0 += w0 * blo(u0); a1 += w0 * bhi(u0);
        b0 += w1 * blo(u1); b1 += w1 * bhi(u1);
    }
    if (j < c) {
        int2 p = e[j];
        float w0 = __int_as_float(p.y);
        unsigned u0 = h2u[(size_t)p.x * 64 + lane];
        a0 += w0 * blo(u0); a1 += w0 * bhi(u0);
    }

    // overflow net (ovf_n is ~always 0)
    int ovf_n = min(*ovf_cnt, OVF_CAP);
    for (int i = 0; i < ovf_n; ++i) {
        int4 v = ovf[i];
        if (v.y == node) {
            float w0 = __int_as_float(v.z);
            unsigned u0 = h2u[(size_t)v.x * 64 + lane];
            a0 += w0 * blo(u0); a1 += w0 * bhi(u0);
        }
    }

    float di = deg2dinv(deg[node]);
    float2 bc = *(const float2*)&b_conv[lane * 2];
    float v0 = bc.x + di * (a0 + b0);
    float v1 = bc.y + di * (a1 + b1);
    aggu[(size_t)node * 64 + lane] = (unsigned)f2bf(v0) | ((unsigned)f2bf(v1) << 16);
}

// ---------------- GEMM2: out[M,512](f32) = agg[M,128](bf16) @ Wl[128,512](f32) + b_lin ----
// Same recipe as gemm1: 512 threads (8 waves, 4x2), 2-deep register prefetch over
// the 4 K-steps. Write-dominated (102.4 MB f32 out); the pipeline keeps loads in
// flight across K-iterations instead of draining at every barrier.

__global__ __launch_bounds__(512) void gemm2_kernel(const unsigned short* __restrict__ A,
                                                    const float* __restrict__ B,
                                                    const float* __restrict__ bias,
                                                    float* __restrict__ C,
                                                    int M) {
    __shared__ short As[128][40];
    __shared__ short Bs[128][40];
    const int bm = blockIdx.x * 128;
    const int bnb = blockIdx.y * 128;
    const int tid = threadIdx.x;
    const int wave = tid >> 6, lane = tid & 63;
    const int wm = wave >> 1, wn = wave & 1;        // 4x2 wave grid: 32-row x 64-col per wave
    const int mlane = lane & 15, quad = lane >> 4;

    // staging geometry: A = 512 16B tasks -> 1/thread; B = 512 (n,kg) tasks -> 1/thread
    const int ar = tid >> 2, ach = tid & 3;          // A row, 16B chunk
    const int bn = tid & 127, bkg = tid >> 7;        // B col, k-group (0..3)

    f32x4 acc[2][4];
#pragma unroll
    for (int i = 0; i < 2; ++i)
#pragma unroll
        for (int j = 0; j < 4; ++j) acc[i][j] = (f32x4){0.f, 0.f, 0.f, 0.f};

    s16x8 pa0, pa1;
    float pb0[8], pb1[8];

    auto loadT = [&](s16x8& pa, float (&pb)[8], int k0) {
        int grow = bm + ar;
        pa = (s16x8){0, 0, 0, 0, 0, 0, 0, 0};
        if (grow < M) pa = *(const s16x8*)(A + (size_t)grow * HH + k0 + ach * 8);
#pragma unroll
        for (int j = 0; j < 8; ++j)
            pb[j] = B[(size_t)(k0 + bkg * 8 + j) * FIN + bnb + bn];
    };
    auto storeT = [&](s16x8& pa, float (&pb)[8]) {
        *(s16x8*)&As[ar][ach * 8] = pa;
        unsigned short tmp[8];
#pragma unroll
        for (int j = 0; j < 8; ++j) tmp[j] = f2bf(pb[j]);
        *(s16x8*)&Bs[bn][bkg * 8] = *(s16x8*)tmp;
    };
    auto mmaT = [&]() {
        s16x8 af[2], bfr[4];
#pragma unroll
        for (int mt = 0; mt < 2; ++mt)
            af[mt] = *(const s16x8*)&As[wm * 32 + mt * 16 + mlane][quad * 8];
#pragma unroll
        for (int nt = 0; nt < 4; ++nt)
            bfr[nt] = *(const s16x8*)&Bs[wn * 64 + nt * 16 + mlane][quad * 8];
#pragma unroll
        for (int mt = 0; mt < 2; ++mt)
#pragma unroll
            for (int nt = 0; nt < 4; ++nt)
                acc[mt][nt] = __builtin_amdgcn_mfma_f32_16x16x32_bf16(af[mt], bfr[nt], acc[mt][nt], 0, 0, 0);
    };

    // 2-deep pipeline over 4 K-steps
    loadT(pa0, pb0, 0);
    loadT(pa1, pb1, 32);
    for (int kk = 0; kk < 4; kk += 2) {
        storeT(pa0, pb0);
        __syncthreads();
        if (kk + 2 < 4) loadT(pa0, pb0, (kk + 2) * 32);
        mmaT();
        __syncthreads();
        storeT(pa1, pb1);
        __syncthreads();
        if (kk + 3 < 4) loadT(pa1, pb1, (kk + 3) * 32);
        mmaT();
        __syncthreads();
    }

#pragma unroll
    for (int mt = 0; mt < 2; ++mt) {
#pragma unroll
        for (int r = 0; r < 4; ++r) {
            int row = bm + wm * 32 + mt * 16 + quad * 4 + r;
            if (row < M) {
#pragma unroll
                for (int nt = 0; nt < 4; ++nt) {
                    int col = bnb + wn * 64 + nt * 16 + mlane;
                    C[(size_t)row * FIN + col] = acc[mt][nt][r] + bias[col];
                }
            }
        }
    }
}

// ---------------- launch ----------------

extern "C" void kernel_launch(void* const* d_in, const int* in_sizes, int n_in,
                              void* d_out, int out_size, void* d_ws, size_t ws_size,
                              hipStream_t stream) {
    const float* x      = (const float*)d_in[0];
    const int*   ei     = (const int*)d_in[1];
    const float* ew     = (const float*)d_in[2];
    const float* W_conv = (const float*)d_in[3];
    const float* b_conv = (const float*)d_in[4];
    const float* W_lin  = (const float*)d_in[5];
    const float* b_lin  = (const float*)d_in[6];
    float* out = (float*)d_out;

    const int* src = ei;
    const int* dst = ei + EE;

    // workspace layout (bytes, 256-aligned):
    char* ws = (char*)d_ws;
    int*            cnt      = (int*)           (ws + 0);          //   200,704
    float*          deg      = (float*)         (ws + 200704);     //   200,704
    // (dinv slot now unused: dinv computed inline from deg)
    int*            ovf_cnt  = (int*)           (ws + 602112);     //       256
    int*            binTotal = (int*)           (ws + 602368);     //     1,792
    int*            binBase  = (int*)           (ws + 604160);     //     1,792
    int4*           ovf      = (int4*)          (ws + 605952);     // 1,032,192 (64512 entries) -> 1,638,144
    int2*           bucket   = (int2*)          (ws + 1650944);    // 32,000,000 -> 33,650,944
    unsigned short* h2       = (unsigned short*)(ws + 33650944);   // 12,800,000
    unsigned short* agg      = (unsigned short*)(ws + 46450944);   // 12,800,000
    // end: 59,250,944 bytes (unchanged footprint)

    // hist/off ALIAS the bucket region (dead until bucket_build writes bucket):
    int*            hist     = (int*)           (ws + 1650944);    //   400,640 (256*391*4)
    int*            off      = (int*)           (ws + 2051584);    //   400,640
    // bins ALIASES h2 (dead until gemm1): 1.6M * 8B = 12,800,000 exactly
    int2*           bins     = (int2*)          (ws + 33650944);

    hipMemsetAsync(ovf_cnt, 0, sizeof(int), stream);

    const int nb_w = (NN * 64 + 255) / 256;   // one wave per node

    // build: atomic-free counting sort by bin, then per-bin bucket build (LDS atomics)
    hist_kernel<<<NBLK, 256, 0, stream>>>(dst, hist);
    scan_bins<<<NB, 64, 0, stream>>>(hist, off, binTotal);
    bin_base<<<1, 512, 0, stream>>>(binTotal, binBase);
    place_kernel<<<NBLK, 256, 0, stream>>>(src, dst, ew, off, binBase, bins);
    bucket_build<<<NB, 512, 0, stream>>>(binBase, binTotal, bins, cnt, bucket, deg, ovf_cnt, ovf);
    ovf_deg<<<4, 256, 0, stream>>>(ovf_cnt, ovf, deg);

    // GEMM1: h2 = bf16(dinv .* (x @ W_conv)), dinv = rsqrt(deg) inline
    gemm1_kernel<<<dim3((NN + 127) / 128, 1), 512, 0, stream>>>(x, W_conv, deg, h2, NN);

    // aggregation (bf16 -> bf16)
    agg_kernel<<<nb_w, 256, 0, stream>>>((const unsigned int*)h2, cnt, bucket, deg, b_conv,
                                         ovf_cnt, ovf, (unsigned int*)agg, NN);

    // GEMM2: out = agg @ W_lin + b_lin
    gemm2_kernel<<<dim3((NN + 127) / 128, FIN / 128), 512, 0, stream>>>(agg, W_lin, b_lin, out, NN);
}